// Round 8
// baseline (173.998 us; speedup 1.0000x reference)
//
#include <hip/hip_runtime.h>
#include <hip/hip_bf16.h>
#include <math.h>

typedef __attribute__((ext_vector_type(8))) short short8;
typedef __attribute__((ext_vector_type(4))) float f32x4;
typedef unsigned short ushort_t;

#define B_  4
#define T_  4096
#define C_  1024
#define HS_ 128

// scale folded into q at GEMM epilogue: C^-0.5 * log2(e) -> scores in log2 units
#define QSCALE 0.04508422002778011f

// per-tile segment counts (sum = 192 per batch -> grid 768 = 3 blocks/CU).
__device__ const unsigned char NS_[32] = {
    1,1,1,2,2,2,3,3,3,4,4,4,5,5,5,6,6,7,7,7,8,8,8,9,9,9,10,10,11,11,10,11};

__device__ __forceinline__ ushort_t f2bf(float f) {      // RNE
    unsigned int u = __float_as_uint(f);
    u = (u + 0x7FFFu + ((u >> 16) & 1u)) >> 16;
    return (ushort_t)u;
}
__device__ __forceinline__ ushort_t f2bf_fast(float f) { // positive, ~RNE
    return (ushort_t)((__float_as_uint(f) + 0x8000u) >> 16);
}
__device__ __forceinline__ float bf2f(ushort_t u) {
    return __uint_as_float(((unsigned)u) << 16);
}
__device__ __forceinline__ void async16(const void* g, void* l) {
    __builtin_amdgcn_global_load_lds(
        (const __attribute__((address_space(1))) unsigned int*)g,
        (__attribute__((address_space(3))) unsigned int*)l, 16, 0, 0);
}
__device__ __forceinline__ float exp2fast(float x) {
    return __builtin_amdgcn_exp2f(x);
}
__device__ __forceinline__ void stnt8(ushort_t* p, short8 v) {
    __builtin_nontemporal_store(v, (short8*)p);
}

// ---------------------------------------------------------------------------
// Kernel 1: W [1024][128] fp32 -> WT bf16 [m][h][k] via LDS transpose.
// ---------------------------------------------------------------------------
__global__ __launch_bounds__(256) void wt_kernel(
    const float* __restrict__ Wq, const float* __restrict__ Wk,
    const float* __restrict__ Wv, ushort_t* __restrict__ WT3)
{
    __shared__ ushort_t sWT[128 * 68];
    const int blk = blockIdx.x, tid = threadIdx.x;
    const int m = blk >> 4, slab = blk & 15;
    const float* __restrict__ W = (m == 0) ? Wq : (m == 1) ? Wk : Wv;
    const int kc = slab * 64;
    const int r = tid >> 2, h0 = (tid & 3) * 32;
#pragma unroll
    for (int j = 0; j < 8; ++j) {
        float4 wv = *(const float4*)(W + (size_t)(kc + r) * 128 + h0 + j * 4);
        sWT[(h0 + j * 4 + 0) * 68 + r] = f2bf(wv.x);
        sWT[(h0 + j * 4 + 1) * 68 + r] = f2bf(wv.y);
        sWT[(h0 + j * 4 + 2) * 68 + r] = f2bf(wv.z);
        sWT[(h0 + j * 4 + 3) * 68 + r] = f2bf(wv.w);
    }
    __syncthreads();
#pragma unroll
    for (int j = 0; j < 4; ++j) {
        int d = j * 256 + tid;
        int h = d >> 3, c8 = d & 7;
        short8 o;
#pragma unroll
        for (int e = 0; e < 8; ++e) o[e] = (short)sWT[h * 68 + c8 * 8 + e];
        *(short8*)(WT3 + (size_t)(m * 128 + h) * 1024 + kc + c8 * 8) = o;
    }
}

// ---------------------------------------------------------------------------
// Kernel 2: qkv = x @ W.  64x128 tile (4 waves of 16x128), BK=64, double-
// buffered.  grid = (256, 3) = 3/CU.  Best of 4 tested structures.
// ---------------------------------------------------------------------------
__global__ __launch_bounds__(256, 3) void qkv_gemm(
    const float* __restrict__ x, const ushort_t* __restrict__ WT3,
    ushort_t* __restrict__ q, ushort_t* __restrict__ k,
    ushort_t* __restrict__ vT)
{
    __shared__ ushort_t smem[24576];      // [2] x (A 4096 | B 8192 shorts)

    const int tid  = threadIdx.x;
    const int t0   = blockIdx.x * 64;
    const int mm   = blockIdx.y;
    const int w    = tid >> 6, lane = tid & 63;
    const int quad = lane >> 4, l15 = lane & 15;

    const ushort_t* __restrict__ WTm = WT3 + (size_t)mm * (128 * 1024);

    const int arow = tid >> 3, ac = tid & 7;
    const float* __restrict__ gx = x + (size_t)(t0 + arow) * C_ + ac * 8;
    const int aswz = ((ac ^ (arow & 7)) * 8);

    const ushort_t* gB[4];
    int bdst[4];
#pragma unroll
    for (int j = 0; j < 4; ++j) {
        int d = j * 256 + tid, row = d >> 3, c = d & 7;
        gB[j] = WTm + (size_t)row * C_ + ((c ^ (row & 7)) * 8);
        bdst[j] = 4096 + d * 8;
    }

    f32x4 acc[8];
#pragma unroll
    for (int nt = 0; nt < 8; ++nt) acc[nt] = (f32x4)0.f;

    float4 ar[2][2];
#pragma unroll
    for (int p = 0; p < 2; ++p) {
        ar[p][0] = *(const float4*)(gx + (size_t)(p * 32) * C_);
        ar[p][1] = *(const float4*)(gx + (size_t)(p * 32) * C_ + 4);
    }
#pragma unroll
    for (int j = 0; j < 4; ++j) async16(gB[j], &smem[bdst[j]]);
#pragma unroll
    for (int p = 0; p < 2; ++p) {
        short8 sv;
        sv[0]=f2bf(ar[p][0].x); sv[1]=f2bf(ar[p][0].y);
        sv[2]=f2bf(ar[p][0].z); sv[3]=f2bf(ar[p][0].w);
        sv[4]=f2bf(ar[p][1].x); sv[5]=f2bf(ar[p][1].y);
        sv[6]=f2bf(ar[p][1].z); sv[7]=f2bf(ar[p][1].w);
        *(short8*)&smem[(p * 32 + arow) * 64 + aswz] = sv;
    }
    __syncthreads();

    const int arow_q = w * 16 + l15;
    for (int it = 0; it < 16; ++it) {
        const int buf = it & 1, nb = buf ^ 1;
        const bool more = (it < 15);
        if (more) {
            const int kc = (it + 1) * 64;
#pragma unroll
            for (int p = 0; p < 2; ++p) {
                ar[p][0] = *(const float4*)(gx + (size_t)(p * 32) * C_ + kc);
                ar[p][1] = *(const float4*)(gx + (size_t)(p * 32) * C_ + kc + 4);
            }
#pragma unroll
            for (int j = 0; j < 4; ++j)
                async16(gB[j] + kc, &smem[nb * 12288 + bdst[j]]);
        }
        const ushort_t* sA = &smem[buf * 12288];
        const ushort_t* sB = &smem[buf * 12288 + 4096];
#pragma unroll
        for (int kf = 0; kf < 2; ++kf) {
            short8 af = *(const short8*)&sA[arow_q * 64 + (((kf * 4 + quad) ^ (arow_q & 7)) * 8)];
#pragma unroll
            for (int nt = 0; nt < 8; ++nt) {
                int row = nt * 16 + l15;
                short8 bf = *(const short8*)&sB[row * 64 + (((kf * 4 + quad) ^ (row & 7)) * 8)];
                acc[nt] = __builtin_amdgcn_mfma_f32_16x16x32_bf16(af, bf, acc[nt], 0, 0, 0);
            }
        }
        if (more) {
#pragma unroll
            for (int p = 0; p < 2; ++p) {
                short8 sv;
                sv[0]=f2bf(ar[p][0].x); sv[1]=f2bf(ar[p][0].y);
                sv[2]=f2bf(ar[p][0].z); sv[3]=f2bf(ar[p][0].w);
                sv[4]=f2bf(ar[p][1].x); sv[5]=f2bf(ar[p][1].y);
                sv[6]=f2bf(ar[p][1].z); sv[7]=f2bf(ar[p][1].w);
                *(short8*)&smem[nb * 12288 + (p * 32 + arow) * 64 + aswz] = sv;
            }
        }
        __syncthreads();
    }

    if (mm < 2) {
        ushort_t* __restrict__ outp = (mm == 0) ? q : k;
        const float s = (mm == 0) ? QSCALE : 1.0f;
        ushort_t* sE = &smem[0];            // 64 x 136
#pragma unroll
        for (int nt = 0; nt < 8; ++nt)
#pragma unroll
            for (int rr = 0; rr < 4; ++rr)
                sE[(w * 16 + quad * 4 + rr) * 136 + nt * 16 + l15] =
                    f2bf(acc[nt][rr] * s);
        __syncthreads();
#pragma unroll
        for (int j = 0; j < 4; ++j) {
            int d = j * 256 + tid;
            int row = d >> 4, cs = d & 15;
            *(short8*)(outp + (size_t)(t0 + row) * HS_ + cs * 8) =
                *(const short8*)&sE[row * 136 + cs * 8];
        }
    } else {
        ushort_t* sT = &smem[0];            // 64 x 132
#pragma unroll
        for (int nt = 0; nt < 8; ++nt)
#pragma unroll
            for (int rr = 0; rr < 4; ++rr)
                sT[(w * 16 + quad * 4 + rr) * 132 + nt * 16 + l15] =
                    f2bf(acc[nt][rr]);
        __syncthreads();
        const int bb = t0 >> 12;
        const int tl = t0 & (T_ - 1);
#pragma unroll
        for (int j = 0; j < 4; ++j) {
            int d = j * 256 + tid;
            int h = d >> 3, t8 = d & 7;
            short8 o;
#pragma unroll
            for (int e = 0; e < 8; ++e)
                o[e] = (short)sT[(t8 * 8 + e) * 132 + h];
            *(short8*)(vT + ((size_t)(bb * HS_) + h) * T_ + tl + t8 * 8) = o;
        }
    }
}

// ---------------------------------------------------------------------------
// Kernel 3 (R8): causal flash attention with COUNTED-VMCNT pipeline (T4).
// __syncthreads (vmcnt(0) drain each chunk = the 85%-idle stall) replaced by
// raw s_barrier + "s_waitcnt vmcnt(4) lgkmcnt(0)": K async16 prefetch issued
// 2 chunks ahead into a TRIPLE buffer stays in flight across barriers
// (~2 chunk-bodies of latency slack).  V: reg-prefetch 1-deep, commit at top
// of next body (single reg set).  V LDS pad-40 -> [128][32] XOR-swizzle
// (<=2-way = free) so LDS = 50 KB -> still 3 blocks/CU.
// vmcnt ledger (per wave, steady state body c):
//   outstanding at commit: K(c+1)x2,V(c+2)x2,K(c+2)x2 -> compiler waits V(c+1)
//   outstanding at barrier: same 6 -> vmcnt(4) retires K(c+1) (next QK's data)
// Cross-wave: every wave retires its K(c+1) + lgkm pre-barrier; triple buffer
// makes prefetch-target != any buffer readable this side of the barrier.
// ---------------------------------------------------------------------------
__global__ __launch_bounds__(256, 3) void attn_seg(
    const ushort_t* __restrict__ q, const ushort_t* __restrict__ k,
    const ushort_t* __restrict__ vT, ushort_t* __restrict__ Opart,
    float* __restrict__ lseg)
{
    __shared__ ushort_t smem[25600];       // 50 KB
    ushort_t* sKb = smem;                  // [3][4096] : 32 keys x 128 h, swz
    ushort_t* sVb = smem + 12288;          // [2][4096] : 128 h x 32, XOR-swz
    ushort_t* sP  = smem + 20480;          // [4][1280] : 32 rows x 40

    const int tid  = threadIdx.x;
    const int bid  = blockIdx.x;
    const int bb   = (bid & 7) >> 1;
    const int seg  = ((bid >> 3) << 1) | (bid & 1);
    const int slot = bb * 192 + seg;
    int r_ = seg;
    int i = 0;
    while (r_ >= NS_[i]) { r_ -= NS_[i]; ++i; }
    const int s    = r_;
    const int ns   = NS_[i];
    const int qb   = i << 7;
    const int nkc  = (i + 1) << 2;
    const int c0   = (nkc * s) / ns;
    const int c1   = (nkc * (s + 1)) / ns;

    const int w    = tid >> 6, lane = tid & 63;
    const int quad = lane >> 4, l15 = lane & 15;
    const size_t bT = (size_t)bb << 12;

    // staging descriptors
    const int kr0 = tid >> 4,          kc0 = tid & 15;
    const int kr1 = (tid + 256) >> 4,  kc1 = (tid + 256) & 15;
    const ushort_t* kp0 = k + (bT + (size_t)c0 * 32 + kr0) * HS_ + ((kc0 ^ (kr0 & 15)) * 8);
    const ushort_t* kp1 = k + (bT + (size_t)c0 * 32 + kr1) * HS_ + ((kc1 ^ (kr1 & 15)) * 8);
    const int vr0 = tid >> 2,          vc0 = tid & 3;
    const int vr1 = (tid + 256) >> 2,  vc1 = (tid + 256) & 3;
    const ushort_t* vp0 = vT + ((size_t)(bb * HS_) + vr0) * T_ + c0 * 32 + vc0 * 8;
    const ushort_t* vp1 = vT + ((size_t)(bb * HS_) + vr1) * T_ + c0 * 32 + vc1 * 8;
    const int vdst0 = vr0 * 32 + ((vc0 ^ (vr0 & 3)) * 8);
    const int vdst1 = vr1 * 32 + ((vc1 ^ (vr1 & 3)) * 8);

    // Q fragments
    short8 qf[2][4];
#pragma unroll
    for (int mt = 0; mt < 2; ++mt)
#pragma unroll
        for (int kf = 0; kf < 4; ++kf)
            qf[mt][kf] = *(const short8*)(
                q + (bT + qb + w * 32 + mt * 16 + l15) * HS_ + kf * 32 + quad * 8);

    f32x4 O[2][8];
    f32x4 O_l[2];
#pragma unroll
    for (int mt = 0; mt < 2; ++mt) {
        O_l[mt] = (f32x4)0.f;
#pragma unroll
        for (int nt = 0; nt < 8; ++nt) O[mt][nt] = (f32x4)0.f;
    }
    short8 ones;
#pragma unroll
    for (int e = 0; e < 8; ++e) ones[e] = (short)0x3F80;

    int rK = c0 % 3;        // K read-buffer rotation
    int vb = 0;             // V read-buffer parity
    short8 pv0, pv1;        // V regs for chunk c+1 (single set)

    // ---- prologue: K(c0), V(c0); then K(c0+1), V(c0+1) ----
    {
        short8 v0 = *(const short8*)vp0;
        short8 v1 = *(const short8*)vp1;
        async16(kp0, sKb + rK * 4096 + tid * 8);
        async16(kp1, sKb + rK * 4096 + (tid + 256) * 8);
        kp0 += 32 * HS_; kp1 += 32 * HS_; vp0 += 32; vp1 += 32;
        *(short8*)(sVb + vdst0) = v0;        // compiler inserts counted vmcnt
        *(short8*)(sVb + vdst1) = v1;
        if (c0 + 1 < c1) {
            pv0 = *(const short8*)vp0;
            pv1 = *(const short8*)vp1;
            int k1 = (rK == 2) ? 0 : rK + 1;
            async16(kp0, sKb + k1 * 4096 + tid * 8);
            async16(kp1, sKb + k1 * 4096 + (tid + 256) * 8);
            kp0 += 32 * HS_; kp1 += 32 * HS_; vp0 += 32; vp1 += 32;
        }
        asm volatile("s_waitcnt vmcnt(4) lgkmcnt(0)" ::: "memory");
        __builtin_amdgcn_s_barrier();
    }

    for (int c = c0; c < c1; ++c) {
        const int kb = c << 5;
        const bool haveNext = (c + 1 < c1);
        const bool havePf   = (c + 2 < c1);

        // commit V(c+1) into the other buffer (compiler waits its loads only)
        if (haveNext) {
            *(short8*)(sVb + (vb ^ 1) * 4096 + vdst0) = pv0;
            *(short8*)(sVb + (vb ^ 1) * 4096 + vdst1) = pv1;
        }
        // issue prefetch for chunk c+2 (stays in flight across the barrier)
        if (havePf) {
            pv0 = *(const short8*)vp0;
            pv1 = *(const short8*)vp1;
            int wK = rK + 2; if (wK >= 3) wK -= 3;
            async16(kp0, sKb + wK * 4096 + tid * 8);
            async16(kp1, sKb + wK * 4096 + (tid + 256) * 8);
            kp0 += 32 * HS_; kp1 += 32 * HS_; vp0 += 32; vp1 += 32;
        }
        const ushort_t* sK = sKb + rK * 4096;
        const ushort_t* sV = sVb + vb * 4096;

        // ---- QK^T (scores in log2 units) ----
        f32x4 S[2][2];
        S[0][0] = (f32x4)0.f; S[0][1] = (f32x4)0.f;
        S[1][0] = (f32x4)0.f; S[1][1] = (f32x4)0.f;
#pragma unroll
        for (int nt = 0; nt < 2; ++nt) {
            int row = nt * 16 + l15;
#pragma unroll
            for (int kf = 0; kf < 4; ++kf) {
                short8 bf = *(const short8*)&sK[row * 128 + (((kf * 4 + quad) ^ l15) * 8)];
                S[0][nt] = __builtin_amdgcn_mfma_f32_16x16x32_bf16(qf[0][kf], bf, S[0][nt], 0, 0, 0);
                S[1][nt] = __builtin_amdgcn_mfma_f32_16x16x32_bf16(qf[1][kf], bf, S[1][nt], 0, 0, 0);
            }
        }
        // ---- causal mask (diagonal chunks only) ----
        if (kb + 31 > qb + w * 32) {
#pragma unroll
            for (int mt = 0; mt < 2; ++mt)
#pragma unroll
                for (int nt = 0; nt < 2; ++nt)
#pragma unroll
                    for (int rr = 0; rr < 4; ++rr)
                        if (kb + nt * 16 + l15 > qb + w * 32 + mt * 16 + quad * 4 + rr)
                            S[mt][nt][rr] = -1e30f;
        }
        // ---- softmax: p = exp2(S) ----
#pragma unroll
        for (int mt = 0; mt < 2; ++mt)
#pragma unroll
            for (int nt = 0; nt < 2; ++nt)
#pragma unroll
                for (int rr = 0; rr < 4; ++rr)
                    sP[w * 1280 + (mt * 16 + quad * 4 + rr) * 40 + nt * 16 + l15] =
                        f2bf_fast(exp2fast(S[mt][nt][rr]));
        // ---- PV + row-sums via ones-MFMA ----
#pragma unroll
        for (int mt = 0; mt < 2; ++mt) {
            short8 pf = *(short8*)&sP[w * 1280 + (mt * 16 + l15) * 40 + quad * 8];
            O_l[mt] = __builtin_amdgcn_mfma_f32_16x16x32_bf16(pf, ones, O_l[mt], 0, 0, 0);
#pragma unroll
            for (int nt = 0; nt < 8; ++nt) {
                int rv = nt * 16 + l15;
                short8 vf = *(const short8*)&sV[rv * 32 + ((quad ^ (rv & 3)) * 8)];
                O[mt][nt] = __builtin_amdgcn_mfma_f32_16x16x32_bf16(pf, vf, O[mt][nt], 0, 0, 0);
            }
        }
        // counted drain: retire K(c+1) only; K(c+2)/V(c+2) stay in flight
        asm volatile("s_waitcnt vmcnt(4) lgkmcnt(0)" ::: "memory");
        __builtin_amdgcn_s_barrier();
        rK = (rK == 2) ? 0 : rK + 1;
        vb ^= 1;
    }

    // ---- epilogue: bf16 partials via LDS coalesce, l from ones-MFMA ----
    ushort_t* sE = smem;                     // 128 x 136
#pragma unroll
    for (int mt = 0; mt < 2; ++mt)
#pragma unroll
        for (int nt = 0; nt < 8; ++nt)
#pragma unroll
            for (int rr = 0; rr < 4; ++rr)
                sE[(w * 32 + mt * 16 + quad * 4 + rr) * 136 + nt * 16 + l15] =
                    f2bf(O[mt][nt][rr]);
    if (l15 == 0)
#pragma unroll
        for (int mt = 0; mt < 2; ++mt)
#pragma unroll
            for (int rr = 0; rr < 4; ++rr)
                lseg[slot * 128 + w * 32 + mt * 16 + quad * 4 + rr] = O_l[mt][rr];
    __syncthreads();
#pragma unroll
    for (int j = 0; j < 8; ++j) {
        int d = j * 256 + tid;
        int row = d >> 4, cs = d & 15;
        stnt8(Opart + (size_t)slot * 16384 + row * 128 + cs * 8,
              *(const short8*)&sE[row * 136 + cs * 8]);
    }
}

// ---------------------------------------------------------------------------
// Kernel 4: combine: out = (sum_s O_s) / (sum_s l_s).  grid = 1024.
// ---------------------------------------------------------------------------
__global__ __launch_bounds__(256) void combine_kernel(
    const ushort_t* __restrict__ Opart, const float* __restrict__ lseg,
    float* __restrict__ out)
{
    const int blk  = blockIdx.x;           // 1024
    const int tile = blk >> 3, rg = blk & 7;
    const int i    = tile & 31;
    int sb = (tile >> 5) * 192;
    for (int j = 0; j < i; ++j) sb += NS_[j];
    const int ns  = NS_[i];
    const int row = rg * 16 + (threadIdx.x >> 4);
    const int col = (threadIdx.x & 15) * 8;

    const ushort_t* op = Opart + (size_t)sb * 16384 + row * 128 + col;
    const float*    lp = lseg + sb * 128 + row;

    float den = lp[0];
    short8 cur = *(const short8*)op;
    float acc[8];
#pragma unroll
    for (int e = 0; e < 8; ++e) acc[e] = 0.f;
    for (int s = 1; s < ns; ++s) {
        short8 nxt = *(const short8*)(op + (size_t)s * 16384);
        float  dn  = lp[s * 128];
#pragma unroll
        for (int e = 0; e < 8; ++e) acc[e] += bf2f((ushort_t)cur[e]);
        den += dn;
        cur = nxt;
    }
#pragma unroll
    for (int e = 0; e < 8; ++e) acc[e] += bf2f((ushort_t)cur[e]);

    const float inv = 1.0f / den;
    float* o = out + ((size_t)tile * 128 + row) * 128 + col;
    float4 v0 = make_float4(acc[0] * inv, acc[1] * inv, acc[2] * inv, acc[3] * inv);
    float4 v1 = make_float4(acc[4] * inv, acc[5] * inv, acc[6] * inv, acc[7] * inv);
    *(float4*)o = v0;
    *(float4*)(o + 4) = v1;
}

// ---------------------------------------------------------------------------
extern "C" void kernel_launch(void* const* d_in, const int* in_sizes, int n_in,
                              void* d_out, int out_size, void* d_ws, size_t ws_size,
                              hipStream_t stream)
{
    const float* x  = (const float*)d_in[0];
    const float* Wq = (const float*)d_in[1];
    const float* Wk = (const float*)d_in[2];
    const float* Wv = (const float*)d_in[3];
    float* out = (float*)d_out;

    ushort_t* WT3 = (ushort_t*)d_ws;               // 393,216 shorts
    ushort_t* q   = WT3 + 393216;                  // 2,097,152
    ushort_t* k   = q + 2097152;
    ushort_t* vT  = k + 2097152;                   // [B][HS][T]
    ushort_t* Opart = vT + 2097152;                // 768 slots x 16384 bf16 (25.2 MB)
    float* lseg   = (float*)(Opart + 768 * 16384); // 98,304 floats

    wt_kernel<<<48, 256, 0, stream>>>(Wq, Wk, Wv, WT3);
    qkv_gemm<<<dim3(256, 3), 256, 0, stream>>>(x, WT3, q, k, vT);
    attn_seg<<<768, 256, 0, stream>>>(q, k, vT, Opart, lseg);
    combine_kernel<<<1024, 256, 0, stream>>>(Opart, lseg, out);
}

// Round 9
// 163.813 us; speedup vs baseline: 1.0622x; 1.0622x over previous
//
#include <hip/hip_runtime.h>
#include <hip/hip_bf16.h>
#include <math.h>

typedef __attribute__((ext_vector_type(8))) short short8;
typedef __attribute__((ext_vector_type(4))) float f32x4;
typedef unsigned short ushort_t;

#define B_  4
#define T_  4096
#define C_  1024
#define HS_ 128

// scale folded into q at GEMM epilogue: C^-0.5 * log2(e) -> scores in log2 units
#define QSCALE 0.04508422002778011f

// per-tile segment counts (sum = 192 per batch -> grid 768 = 3 blocks/CU).
__device__ const unsigned char NS_[32] = {
    1,1,1,2,2,2,3,3,3,4,4,4,5,5,5,6,6,7,7,7,8,8,8,9,9,9,10,10,11,11,10,11};

__device__ __forceinline__ ushort_t f2bf(float f) {      // RNE
    unsigned int u = __float_as_uint(f);
    u = (u + 0x7FFFu + ((u >> 16) & 1u)) >> 16;
    return (ushort_t)u;
}
__device__ __forceinline__ ushort_t f2bf_fast(float f) { // positive, ~RNE
    return (ushort_t)((__float_as_uint(f) + 0x8000u) >> 16);
}
__device__ __forceinline__ float bf2f(ushort_t u) {
    return __uint_as_float(((unsigned)u) << 16);
}
__device__ __forceinline__ void async16(const void* g, void* l) {
    __builtin_amdgcn_global_load_lds(
        (const __attribute__((address_space(1))) unsigned int*)g,
        (__attribute__((address_space(3))) unsigned int*)l, 16, 0, 0);
}
__device__ __forceinline__ float exp2fast(float x) {
    return __builtin_amdgcn_exp2f(x);
}
__device__ __forceinline__ void stnt8(ushort_t* p, short8 v) {
    __builtin_nontemporal_store(v, (short8*)p);
}

// ---------------------------------------------------------------------------
// Kernel 1: W [1024][128] fp32 -> WT bf16 [m][h][k] via LDS transpose.
// ---------------------------------------------------------------------------
__global__ __launch_bounds__(256) void wt_kernel(
    const float* __restrict__ Wq, const float* __restrict__ Wk,
    const float* __restrict__ Wv, ushort_t* __restrict__ WT3)
{
    __shared__ ushort_t sWT[128 * 68];
    const int blk = blockIdx.x, tid = threadIdx.x;
    const int m = blk >> 4, slab = blk & 15;
    const float* __restrict__ W = (m == 0) ? Wq : (m == 1) ? Wk : Wv;
    const int kc = slab * 64;
    const int r = tid >> 2, h0 = (tid & 3) * 32;
#pragma unroll
    for (int j = 0; j < 8; ++j) {
        float4 wv = *(const float4*)(W + (size_t)(kc + r) * 128 + h0 + j * 4);
        sWT[(h0 + j * 4 + 0) * 68 + r] = f2bf(wv.x);
        sWT[(h0 + j * 4 + 1) * 68 + r] = f2bf(wv.y);
        sWT[(h0 + j * 4 + 2) * 68 + r] = f2bf(wv.z);
        sWT[(h0 + j * 4 + 3) * 68 + r] = f2bf(wv.w);
    }
    __syncthreads();
#pragma unroll
    for (int j = 0; j < 4; ++j) {
        int d = j * 256 + tid;
        int h = d >> 3, c8 = d & 7;
        short8 o;
#pragma unroll
        for (int e = 0; e < 8; ++e) o[e] = (short)sWT[h * 68 + c8 * 8 + e];
        *(short8*)(WT3 + (size_t)(m * 128 + h) * 1024 + kc + c8 * 8) = o;
    }
}

// ---------------------------------------------------------------------------
// Kernel 2: qkv = x @ W.  64x128 tile (4 waves of 16x128), BK=64, double-
// buffered.  grid = (256, 3) = 3/CU.  Best of 4 tested structures.
// ---------------------------------------------------------------------------
__global__ __launch_bounds__(256, 3) void qkv_gemm(
    const float* __restrict__ x, const ushort_t* __restrict__ WT3,
    ushort_t* __restrict__ q, ushort_t* __restrict__ k,
    ushort_t* __restrict__ vT)
{
    __shared__ ushort_t smem[24576];      // [2] x (A 4096 | B 8192 shorts)

    const int tid  = threadIdx.x;
    const int t0   = blockIdx.x * 64;
    const int mm   = blockIdx.y;
    const int w    = tid >> 6, lane = tid & 63;
    const int quad = lane >> 4, l15 = lane & 15;

    const ushort_t* __restrict__ WTm = WT3 + (size_t)mm * (128 * 1024);

    const int arow = tid >> 3, ac = tid & 7;
    const float* __restrict__ gx = x + (size_t)(t0 + arow) * C_ + ac * 8;
    const int aswz = ((ac ^ (arow & 7)) * 8);

    const ushort_t* gB[4];
    int bdst[4];
#pragma unroll
    for (int j = 0; j < 4; ++j) {
        int d = j * 256 + tid, row = d >> 3, c = d & 7;
        gB[j] = WTm + (size_t)row * C_ + ((c ^ (row & 7)) * 8);
        bdst[j] = 4096 + d * 8;
    }

    f32x4 acc[8];
#pragma unroll
    for (int nt = 0; nt < 8; ++nt) acc[nt] = (f32x4)0.f;

    float4 ar[2][2];
#pragma unroll
    for (int p = 0; p < 2; ++p) {
        ar[p][0] = *(const float4*)(gx + (size_t)(p * 32) * C_);
        ar[p][1] = *(const float4*)(gx + (size_t)(p * 32) * C_ + 4);
    }
#pragma unroll
    for (int j = 0; j < 4; ++j) async16(gB[j], &smem[bdst[j]]);
#pragma unroll
    for (int p = 0; p < 2; ++p) {
        short8 sv;
        sv[0]=f2bf(ar[p][0].x); sv[1]=f2bf(ar[p][0].y);
        sv[2]=f2bf(ar[p][0].z); sv[3]=f2bf(ar[p][0].w);
        sv[4]=f2bf(ar[p][1].x); sv[5]=f2bf(ar[p][1].y);
        sv[6]=f2bf(ar[p][1].z); sv[7]=f2bf(ar[p][1].w);
        *(short8*)&smem[(p * 32 + arow) * 64 + aswz] = sv;
    }
    __syncthreads();

    const int arow_q = w * 16 + l15;
    for (int it = 0; it < 16; ++it) {
        const int buf = it & 1, nb = buf ^ 1;
        const bool more = (it < 15);
        if (more) {
            const int kc = (it + 1) * 64;
#pragma unroll
            for (int p = 0; p < 2; ++p) {
                ar[p][0] = *(const float4*)(gx + (size_t)(p * 32) * C_ + kc);
                ar[p][1] = *(const float4*)(gx + (size_t)(p * 32) * C_ + kc + 4);
            }
#pragma unroll
            for (int j = 0; j < 4; ++j)
                async16(gB[j] + kc, &smem[nb * 12288 + bdst[j]]);
        }
        const ushort_t* sA = &smem[buf * 12288];
        const ushort_t* sB = &smem[buf * 12288 + 4096];
#pragma unroll
        for (int kf = 0; kf < 2; ++kf) {
            short8 af = *(const short8*)&sA[arow_q * 64 + (((kf * 4 + quad) ^ (arow_q & 7)) * 8)];
#pragma unroll
            for (int nt = 0; nt < 8; ++nt) {
                int row = nt * 16 + l15;
                short8 bf = *(const short8*)&sB[row * 64 + (((kf * 4 + quad) ^ (row & 7)) * 8)];
                acc[nt] = __builtin_amdgcn_mfma_f32_16x16x32_bf16(af, bf, acc[nt], 0, 0, 0);
            }
        }
        if (more) {
#pragma unroll
            for (int p = 0; p < 2; ++p) {
                short8 sv;
                sv[0]=f2bf(ar[p][0].x); sv[1]=f2bf(ar[p][0].y);
                sv[2]=f2bf(ar[p][0].z); sv[3]=f2bf(ar[p][0].w);
                sv[4]=f2bf(ar[p][1].x); sv[5]=f2bf(ar[p][1].y);
                sv[6]=f2bf(ar[p][1].z); sv[7]=f2bf(ar[p][1].w);
                *(short8*)&smem[nb * 12288 + (p * 32 + arow) * 64 + aswz] = sv;
            }
        }
        __syncthreads();
    }

    if (mm < 2) {
        ushort_t* __restrict__ outp = (mm == 0) ? q : k;
        const float s = (mm == 0) ? QSCALE : 1.0f;
        ushort_t* sE = &smem[0];            // 64 x 136
#pragma unroll
        for (int nt = 0; nt < 8; ++nt)
#pragma unroll
            for (int rr = 0; rr < 4; ++rr)
                sE[(w * 16 + quad * 4 + rr) * 136 + nt * 16 + l15] =
                    f2bf(acc[nt][rr] * s);
        __syncthreads();
#pragma unroll
        for (int j = 0; j < 4; ++j) {
            int d = j * 256 + tid;
            int row = d >> 4, cs = d & 15;
            *(short8*)(outp + (size_t)(t0 + row) * HS_ + cs * 8) =
                *(const short8*)&sE[row * 136 + cs * 8];
        }
    } else {
        ushort_t* sT = &smem[0];            // 64 x 132
#pragma unroll
        for (int nt = 0; nt < 8; ++nt)
#pragma unroll
            for (int rr = 0; rr < 4; ++rr)
                sT[(w * 16 + quad * 4 + rr) * 132 + nt * 16 + l15] =
                    f2bf(acc[nt][rr]);
        __syncthreads();
        const int bb = t0 >> 12;
        const int tl = t0 & (T_ - 1);
#pragma unroll
        for (int j = 0; j < 4; ++j) {
            int d = j * 256 + tid;
            int h = d >> 3, t8 = d & 7;
            short8 o;
#pragma unroll
            for (int e = 0; e < 8; ++e)
                o[e] = (short)sT[(t8 * 8 + e) * 132 + h];
            *(short8*)(vT + ((size_t)(bb * HS_) + h) * T_ + tl + t8 * 8) = o;
        }
    }
}

// ---------------------------------------------------------------------------
// Kernel 3: causal flash attention.  R7 sync structure (R8's counted-vmcnt
// triple-buffer REVERTED: +4.4 us — the vmcnt(0) drain was already covered
// by the ~3000-cycle body at 3 blocks/CU).
// R9 change: PV loop inverted — vf fragments read ONCE and reused across
// both mt tiles (was: 8 redundant ds_read_b128 per wave per chunk = ~30%
// of LDS read traffic).  pf hoisted to registers.  No layout/sync changes.
// ---------------------------------------------------------------------------
__global__ __launch_bounds__(256, 3) void attn_seg(
    const ushort_t* __restrict__ q, const ushort_t* __restrict__ k,
    const ushort_t* __restrict__ vT, ushort_t* __restrict__ Opart,
    float* __restrict__ lseg)
{
    __shared__ ushort_t smem[23552];       // 47.1 KB
    ushort_t* sKb = smem;                  // [2][4096] : 32 keys x 128 h, swz
    ushort_t* sVb = smem + 8192;           // [2][5120] : 128 h x 40
    ushort_t* sP  = smem + 18432;          // [4][1280] : 32 rows x 40

    const int tid  = threadIdx.x;
    const int bid  = blockIdx.x;
    // XCD-affinity decode: xcd = bid%8 (empirical round-robin); batch = xcd/2
    const int bb   = (bid & 7) >> 1;
    const int seg  = ((bid >> 3) << 1) | (bid & 1);   // 0..191 within batch
    const int slot = bb * 192 + seg;                  // unchanged slot layout
    int r_ = seg;
    int i = 0;
    while (r_ >= NS_[i]) { r_ -= NS_[i]; ++i; }
    const int s    = r_;
    const int ns   = NS_[i];
    const int qb   = i << 7;
    const int nkc  = (i + 1) << 2;           // 32-key chunks in causal range
    const int c0   = (nkc * s) / ns;
    const int c1   = (nkc * (s + 1)) / ns;

    const int w    = tid >> 6, lane = tid & 63;
    const int quad = lane >> 4, l15 = lane & 15;
    const size_t bT = (size_t)bb << 12;

    // staging descriptors
    const int kr0 = tid >> 4,          kc0 = tid & 15;
    const int kr1 = (tid + 256) >> 4,  kc1 = (tid + 256) & 15;
    const ushort_t* kp0 = k + (bT + (size_t)c0 * 32 + kr0) * HS_ + ((kc0 ^ (kr0 & 15)) * 8);
    const ushort_t* kp1 = k + (bT + (size_t)c0 * 32 + kr1) * HS_ + ((kc1 ^ (kr1 & 15)) * 8);
    const int vr0 = tid >> 2,          vc0 = tid & 3;
    const int vr1 = (tid + 256) >> 2,  vc1 = (tid + 256) & 3;
    const ushort_t* vp0 = vT + ((size_t)(bb * HS_) + vr0) * T_ + c0 * 32 + vc0 * 8;
    const ushort_t* vp1 = vT + ((size_t)(bb * HS_) + vr1) * T_ + c0 * 32 + vc1 * 8;
    const int vdst0 = vr0 * 40 + vc0 * 8;
    const int vdst1 = vr1 * 40 + vc1 * 8;

    // Q fragments (A-layout straight from global)
    short8 qf[2][4];
#pragma unroll
    for (int mt = 0; mt < 2; ++mt)
#pragma unroll
        for (int kf = 0; kf < 4; ++kf)
            qf[mt][kf] = *(const short8*)(
                q + (bT + qb + w * 32 + mt * 16 + l15) * HS_ + kf * 32 + quad * 8);

    f32x4 O[2][8];
    f32x4 O_l[2];
#pragma unroll
    for (int mt = 0; mt < 2; ++mt) {
        O_l[mt] = (f32x4)0.f;
#pragma unroll
        for (int nt = 0; nt < 8; ++nt) O[mt][nt] = (f32x4)0.f;
    }
    short8 ones;
#pragma unroll
    for (int e = 0; e < 8; ++e) ones[e] = (short)0x3F80;

    // prologue: stage chunk c0 into buf 0
    {
        short8 v0 = *(const short8*)vp0;
        short8 v1 = *(const short8*)vp1;
        async16(kp0, sKb + tid * 8);
        async16(kp1, sKb + (tid + 256) * 8);
        kp0 += 32 * HS_; kp1 += 32 * HS_; vp0 += 32; vp1 += 32;
        *(short8*)(sVb + vdst0) = v0;
        *(short8*)(sVb + vdst1) = v1;
    }
    __syncthreads();

    for (int c = c0; c < c1; ++c) {
        const int buf = (c - c0) & 1, nb = buf ^ 1;
        const int kb = c << 5;
        const bool more = (c + 1 < c1);
        short8 pv0, pv1;
        if (more) {                          // prefetch chunk c+1
            pv0 = *(const short8*)vp0;
            pv1 = *(const short8*)vp1;
            async16(kp0, sKb + nb * 4096 + tid * 8);
            async16(kp1, sKb + nb * 4096 + (tid + 256) * 8);
            kp0 += 32 * HS_; kp1 += 32 * HS_; vp0 += 32; vp1 += 32;
        }
        const ushort_t* sK = sKb + buf * 4096;
        const ushort_t* sV = sVb + buf * 5120;

        // ---- QK^T (scores in log2 units) ----
        f32x4 S[2][2];
        S[0][0] = (f32x4)0.f; S[0][1] = (f32x4)0.f;
        S[1][0] = (f32x4)0.f; S[1][1] = (f32x4)0.f;
#pragma unroll
        for (int nt = 0; nt < 2; ++nt) {
            int row = nt * 16 + l15;
#pragma unroll
            for (int kf = 0; kf < 4; ++kf) {
                short8 bf = *(const short8*)&sK[row * 128 + (((kf * 4 + quad) ^ l15) * 8)];
                S[0][nt] = __builtin_amdgcn_mfma_f32_16x16x32_bf16(qf[0][kf], bf, S[0][nt], 0, 0, 0);
                S[1][nt] = __builtin_amdgcn_mfma_f32_16x16x32_bf16(qf[1][kf], bf, S[1][nt], 0, 0, 0);
            }
        }
        // ---- causal mask (diagonal chunks only) ----
        if (kb + 31 > qb + w * 32) {
#pragma unroll
            for (int mt = 0; mt < 2; ++mt)
#pragma unroll
                for (int nt = 0; nt < 2; ++nt)
#pragma unroll
                    for (int rr = 0; rr < 4; ++rr)
                        if (kb + nt * 16 + l15 > qb + w * 32 + mt * 16 + quad * 4 + rr)
                            S[mt][nt][rr] = -1e30f;
        }
        // ---- softmax: p = exp2(S) (no max; shift cancels in combine) ----
#pragma unroll
        for (int mt = 0; mt < 2; ++mt)
#pragma unroll
            for (int nt = 0; nt < 2; ++nt)
#pragma unroll
                for (int rr = 0; rr < 4; ++rr)
                    sP[w * 1280 + (mt * 16 + quad * 4 + rr) * 40 + nt * 16 + l15] =
                        f2bf_fast(exp2fast(S[mt][nt][rr]));
        // ---- PV + row-sums via ones-MFMA (R9: vf read ONCE, shared mt) ----
        {
            short8 pf0 = *(short8*)&sP[w * 1280 + (l15) * 40 + quad * 8];
            short8 pf1 = *(short8*)&sP[w * 1280 + (16 + l15) * 40 + quad * 8];
            O_l[0] = __builtin_amdgcn_mfma_f32_16x16x32_bf16(pf0, ones, O_l[0], 0, 0, 0);
            O_l[1] = __builtin_amdgcn_mfma_f32_16x16x32_bf16(pf1, ones, O_l[1], 0, 0, 0);
#pragma unroll
            for (int nt = 0; nt < 8; ++nt) {
                short8 vf = *(const short8*)&sV[(nt * 16 + l15) * 40 + quad * 8];
                O[0][nt] = __builtin_amdgcn_mfma_f32_16x16x32_bf16(pf0, vf, O[0][nt], 0, 0, 0);
                O[1][nt] = __builtin_amdgcn_mfma_f32_16x16x32_bf16(pf1, vf, O[1][nt], 0, 0, 0);
            }
        }
        // commit prefetched V into the other buffer
        if (more) {
            *(short8*)(sVb + nb * 5120 + vdst0) = pv0;
            *(short8*)(sVb + nb * 5120 + vdst1) = pv1;
        }
        __syncthreads();                     // one barrier per chunk
    }

    // ---- epilogue: bf16 partials via LDS coalesce, l from ones-MFMA ----
    ushort_t* sE = smem;                     // 128 x 136
#pragma unroll
    for (int mt = 0; mt < 2; ++mt)
#pragma unroll
        for (int nt = 0; nt < 8; ++nt)
#pragma unroll
            for (int rr = 0; rr < 4; ++rr)
                sE[(w * 32 + mt * 16 + quad * 4 + rr) * 136 + nt * 16 + l15] =
                    f2bf(O[mt][nt][rr]);
    if (l15 == 0)
#pragma unroll
        for (int mt = 0; mt < 2; ++mt)
#pragma unroll
            for (int rr = 0; rr < 4; ++rr)
                lseg[slot * 128 + w * 32 + mt * 16 + quad * 4 + rr] = O_l[mt][rr];
    __syncthreads();
#pragma unroll
    for (int j = 0; j < 8; ++j) {
        int d = j * 256 + tid;
        int row = d >> 4, cs = d & 15;
        stnt8(Opart + (size_t)slot * 16384 + row * 128 + cs * 8,
              *(const short8*)&sE[row * 136 + cs * 8]);
    }
}

// ---------------------------------------------------------------------------
// Kernel 4: combine: out = (sum_s O_s) / (sum_s l_s).  grid = 1024.
// ---------------------------------------------------------------------------
__global__ __launch_bounds__(256) void combine_kernel(
    const ushort_t* __restrict__ Opart, const float* __restrict__ lseg,
    float* __restrict__ out)
{
    const int blk  = blockIdx.x;           // 1024
    const int tile = blk >> 3, rg = blk & 7;
    const int i    = tile & 31;
    int sb = (tile >> 5) * 192;
    for (int j = 0; j < i; ++j) sb += NS_[j];
    const int ns  = NS_[i];
    const int row = rg * 16 + (threadIdx.x >> 4);
    const int col = (threadIdx.x & 15) * 8;

    const ushort_t* op = Opart + (size_t)sb * 16384 + row * 128 + col;
    const float*    lp = lseg + sb * 128 + row;

    float den = lp[0];
    short8 cur = *(const short8*)op;
    float acc[8];
#pragma unroll
    for (int e = 0; e < 8; ++e) acc[e] = 0.f;
    for (int s = 1; s < ns; ++s) {
        short8 nxt = *(const short8*)(op + (size_t)s * 16384);
        float  dn  = lp[s * 128];
#pragma unroll
        for (int e = 0; e < 8; ++e) acc[e] += bf2f((ushort_t)cur[e]);
        den += dn;
        cur = nxt;
    }
#pragma unroll
    for (int e = 0; e < 8; ++e) acc[e] += bf2f((ushort_t)cur[e]);

    const float inv = 1.0f / den;
    float* o = out + ((size_t)tile * 128 + row) * 128 + col;
    float4 v0 = make_float4(acc[0] * inv, acc[1] * inv, acc[2] * inv, acc[3] * inv);
    float4 v1 = make_float4(acc[4] * inv, acc[5] * inv, acc[6] * inv, acc[7] * inv);
    *(float4*)o = v0;
    *(float4*)(o + 4) = v1;
}

// ---------------------------------------------------------------------------
extern "C" void kernel_launch(void* const* d_in, const int* in_sizes, int n_in,
                              void* d_out, int out_size, void* d_ws, size_t ws_size,
                              hipStream_t stream)
{
    const float* x  = (const float*)d_in[0];
    const float* Wq = (const float*)d_in[1];
    const float* Wk = (const float*)d_in[2];
    const float* Wv = (const float*)d_in[3];
    float* out = (float*)d_out;

    ushort_t* WT3 = (ushort_t*)d_ws;               // 393,216 shorts
    ushort_t* q   = WT3 + 393216;                  // 2,097,152
    ushort_t* k   = q + 2097152;
    ushort_t* vT  = k + 2097152;                   // [B][HS][T]
    ushort_t* Opart = vT + 2097152;                // 768 slots x 16384 bf16 (25.2 MB)
    float* lseg   = (float*)(Opart + 768 * 16384); // 98,304 floats

    wt_kernel<<<48, 256, 0, stream>>>(Wq, Wk, Wv, WT3);
    qkv_gemm<<<dim3(256, 3), 256, 0, stream>>>(x, WT3, q, k, vT);
    attn_seg<<<768, 256, 0, stream>>>(q, k, vT, Opart, lseg);
    combine_kernel<<<1024, 256, 0, stream>>>(Opart, lseg, out);
}

// Round 10
// 160.148 us; speedup vs baseline: 1.0865x; 1.0229x over previous
//
#include <hip/hip_runtime.h>
#include <hip/hip_bf16.h>
#include <math.h>

typedef __attribute__((ext_vector_type(8))) short short8;
typedef __attribute__((ext_vector_type(4))) float f32x4;
typedef unsigned short ushort_t;

#define B_  4
#define T_  4096
#define C_  1024
#define HS_ 128

// scale folded into q at GEMM epilogue: C^-0.5 * log2(e) -> scores in log2 units
#define QSCALE 0.04508422002778011f

// per-tile segment counts (sum = 192 per batch -> grid 768 = 3 blocks/CU).
__device__ const unsigned char NS_[32] = {
    1,1,1,2,2,2,3,3,3,4,4,4,5,5,5,6,6,7,7,7,8,8,8,9,9,9,10,10,11,11,10,11};

__device__ __forceinline__ ushort_t f2bf(float f) {      // RNE
    unsigned int u = __float_as_uint(f);
    u = (u + 0x7FFFu + ((u >> 16) & 1u)) >> 16;
    return (ushort_t)u;
}
__device__ __forceinline__ ushort_t f2bf_fast(float f) { // positive, ~RNE
    return (ushort_t)((__float_as_uint(f) + 0x8000u) >> 16);
}
__device__ __forceinline__ float bf2f(ushort_t u) {
    return __uint_as_float(((unsigned)u) << 16);
}
__device__ __forceinline__ void async16(const void* g, void* l) {
    __builtin_amdgcn_global_load_lds(
        (const __attribute__((address_space(1))) unsigned int*)g,
        (__attribute__((address_space(3))) unsigned int*)l, 16, 0, 0);
}
__device__ __forceinline__ float exp2fast(float x) {
    return __builtin_amdgcn_exp2f(x);
}
__device__ __forceinline__ void stnt8(ushort_t* p, short8 v) {
    __builtin_nontemporal_store(v, (short8*)p);
}

// ---------------------------------------------------------------------------
// Kernel 1: W [1024][128] fp32 -> WT bf16 [m][h][k] via LDS transpose.
// ---------------------------------------------------------------------------
__global__ __launch_bounds__(256) void wt_kernel(
    const float* __restrict__ Wq, const float* __restrict__ Wk,
    const float* __restrict__ Wv, ushort_t* __restrict__ WT3)
{
    __shared__ ushort_t sWT[128 * 68];
    const int blk = blockIdx.x, tid = threadIdx.x;
    const int m = blk >> 4, slab = blk & 15;
    const float* __restrict__ W = (m == 0) ? Wq : (m == 1) ? Wk : Wv;
    const int kc = slab * 64;
    const int r = tid >> 2, h0 = (tid & 3) * 32;
#pragma unroll
    for (int j = 0; j < 8; ++j) {
        float4 wv = *(const float4*)(W + (size_t)(kc + r) * 128 + h0 + j * 4);
        sWT[(h0 + j * 4 + 0) * 68 + r] = f2bf(wv.x);
        sWT[(h0 + j * 4 + 1) * 68 + r] = f2bf(wv.y);
        sWT[(h0 + j * 4 + 2) * 68 + r] = f2bf(wv.z);
        sWT[(h0 + j * 4 + 3) * 68 + r] = f2bf(wv.w);
    }
    __syncthreads();
#pragma unroll
    for (int j = 0; j < 4; ++j) {
        int d = j * 256 + tid;
        int h = d >> 3, c8 = d & 7;
        short8 o;
#pragma unroll
        for (int e = 0; e < 8; ++e) o[e] = (short)sWT[h * 68 + c8 * 8 + e];
        *(short8*)(WT3 + (size_t)(m * 128 + h) * 1024 + kc + c8 * 8) = o;
    }
}

// ---------------------------------------------------------------------------
// Kernel 2: qkv = x @ W.  64x128 tile (4 waves of 16x128), BK=64, double-
// buffered.  grid = (256, 3) = 3/CU.  Best of 4 tested structures.
// ---------------------------------------------------------------------------
__global__ __launch_bounds__(256, 3) void qkv_gemm(
    const float* __restrict__ x, const ushort_t* __restrict__ WT3,
    ushort_t* __restrict__ q, ushort_t* __restrict__ k,
    ushort_t* __restrict__ vT)
{
    __shared__ ushort_t smem[24576];      // [2] x (A 4096 | B 8192 shorts)

    const int tid  = threadIdx.x;
    const int t0   = blockIdx.x * 64;
    const int mm   = blockIdx.y;
    const int w    = tid >> 6, lane = tid & 63;
    const int quad = lane >> 4, l15 = lane & 15;

    const ushort_t* __restrict__ WTm = WT3 + (size_t)mm * (128 * 1024);

    const int arow = tid >> 3, ac = tid & 7;
    const float* __restrict__ gx = x + (size_t)(t0 + arow) * C_ + ac * 8;
    const int aswz = ((ac ^ (arow & 7)) * 8);

    const ushort_t* gB[4];
    int bdst[4];
#pragma unroll
    for (int j = 0; j < 4; ++j) {
        int d = j * 256 + tid, row = d >> 3, c = d & 7;
        gB[j] = WTm + (size_t)row * C_ + ((c ^ (row & 7)) * 8);
        bdst[j] = 4096 + d * 8;
    }

    f32x4 acc[8];
#pragma unroll
    for (int nt = 0; nt < 8; ++nt) acc[nt] = (f32x4)0.f;

    float4 ar[2][2];
#pragma unroll
    for (int p = 0; p < 2; ++p) {
        ar[p][0] = *(const float4*)(gx + (size_t)(p * 32) * C_);
        ar[p][1] = *(const float4*)(gx + (size_t)(p * 32) * C_ + 4);
    }
#pragma unroll
    for (int j = 0; j < 4; ++j) async16(gB[j], &smem[bdst[j]]);
#pragma unroll
    for (int p = 0; p < 2; ++p) {
        short8 sv;
        sv[0]=f2bf(ar[p][0].x); sv[1]=f2bf(ar[p][0].y);
        sv[2]=f2bf(ar[p][0].z); sv[3]=f2bf(ar[p][0].w);
        sv[4]=f2bf(ar[p][1].x); sv[5]=f2bf(ar[p][1].y);
        sv[6]=f2bf(ar[p][1].z); sv[7]=f2bf(ar[p][1].w);
        *(short8*)&smem[(p * 32 + arow) * 64 + aswz] = sv;
    }
    __syncthreads();

    const int arow_q = w * 16 + l15;
    for (int it = 0; it < 16; ++it) {
        const int buf = it & 1, nb = buf ^ 1;
        const bool more = (it < 15);
        if (more) {
            const int kc = (it + 1) * 64;
#pragma unroll
            for (int p = 0; p < 2; ++p) {
                ar[p][0] = *(const float4*)(gx + (size_t)(p * 32) * C_ + kc);
                ar[p][1] = *(const float4*)(gx + (size_t)(p * 32) * C_ + kc + 4);
            }
#pragma unroll
            for (int j = 0; j < 4; ++j)
                async16(gB[j] + kc, &smem[nb * 12288 + bdst[j]]);
        }
        const ushort_t* sA = &smem[buf * 12288];
        const ushort_t* sB = &smem[buf * 12288 + 4096];
#pragma unroll
        for (int kf = 0; kf < 2; ++kf) {
            short8 af = *(const short8*)&sA[arow_q * 64 + (((kf * 4 + quad) ^ (arow_q & 7)) * 8)];
#pragma unroll
            for (int nt = 0; nt < 8; ++nt) {
                int row = nt * 16 + l15;
                short8 bf = *(const short8*)&sB[row * 64 + (((kf * 4 + quad) ^ (row & 7)) * 8)];
                acc[nt] = __builtin_amdgcn_mfma_f32_16x16x32_bf16(af, bf, acc[nt], 0, 0, 0);
            }
        }
        if (more) {
#pragma unroll
            for (int p = 0; p < 2; ++p) {
                short8 sv;
                sv[0]=f2bf(ar[p][0].x); sv[1]=f2bf(ar[p][0].y);
                sv[2]=f2bf(ar[p][0].z); sv[3]=f2bf(ar[p][0].w);
                sv[4]=f2bf(ar[p][1].x); sv[5]=f2bf(ar[p][1].y);
                sv[6]=f2bf(ar[p][1].z); sv[7]=f2bf(ar[p][1].w);
                *(short8*)&smem[nb * 12288 + (p * 32 + arow) * 64 + aswz] = sv;
            }
        }
        __syncthreads();
    }

    if (mm < 2) {
        ushort_t* __restrict__ outp = (mm == 0) ? q : k;
        const float s = (mm == 0) ? QSCALE : 1.0f;
        ushort_t* sE = &smem[0];            // 64 x 136
#pragma unroll
        for (int nt = 0; nt < 8; ++nt)
#pragma unroll
            for (int rr = 0; rr < 4; ++rr)
                sE[(w * 16 + quad * 4 + rr) * 136 + nt * 16 + l15] =
                    f2bf(acc[nt][rr] * s);
        __syncthreads();
#pragma unroll
        for (int j = 0; j < 4; ++j) {
            int d = j * 256 + tid;
            int row = d >> 4, cs = d & 15;
            *(short8*)(outp + (size_t)(t0 + row) * HS_ + cs * 8) =
                *(const short8*)&sE[row * 136 + cs * 8];
        }
    } else {
        ushort_t* sT = &smem[0];            // 64 x 132
#pragma unroll
        for (int nt = 0; nt < 8; ++nt)
#pragma unroll
            for (int rr = 0; rr < 4; ++rr)
                sT[(w * 16 + quad * 4 + rr) * 132 + nt * 16 + l15] =
                    f2bf(acc[nt][rr]);
        __syncthreads();
        const int bb = t0 >> 12;
        const int tl = t0 & (T_ - 1);
#pragma unroll
        for (int j = 0; j < 4; ++j) {
            int d = j * 256 + tid;
            int h = d >> 3, t8 = d & 7;
            short8 o;
#pragma unroll
            for (int e = 0; e < 8; ++e)
                o[e] = (short)sT[(t8 * 8 + e) * 132 + h];
            *(short8*)(vT + ((size_t)(bb * HS_) + h) * T_ + tl + t8 * 8) = o;
        }
    }
}

// ---------------------------------------------------------------------------
// Kernel 3: causal flash attention.  R7 sync structure; R9 vf-read-once
// (confirmed -7 us: the per-chunk serial LDS chain is the binding cost).
// R10: V staged via async16 with PRE-SWIZZLED GLOBAL SOURCE (m173 pattern,
// same as K): removes 2 global_load_dwordx4 + 2 ds_write_b128 + pv regs
// from the chain.  LDS V = [2][128][32] linear (async16 dest = tid*16B).
// Swizzle s(row) = (row ^ (row>>2)) & 3 applied to global t-chunk on write
// and to the LDS col-chunk on read (both-sides involution): vf read goes
// 8-way -> 2-way bank conflict (free).  LDS 47.1 -> 43 KB.
// ---------------------------------------------------------------------------
__global__ __launch_bounds__(256, 3) void attn_seg(
    const ushort_t* __restrict__ q, const ushort_t* __restrict__ k,
    const ushort_t* __restrict__ vT, ushort_t* __restrict__ Opart,
    float* __restrict__ lseg)
{
    __shared__ ushort_t smem[21504];       // 43 KB
    ushort_t* sKb = smem;                  // [2][4096] : 32 keys x 128 h, swz
    ushort_t* sVb = smem + 8192;           // [2][4096] : 128 h x 32, swz
    ushort_t* sP  = smem + 16384;          // [4][1280] : 32 rows x 40

    const int tid  = threadIdx.x;
    const int bid  = blockIdx.x;
    // XCD-affinity decode: xcd = bid%8 (empirical round-robin); batch = xcd/2
    const int bb   = (bid & 7) >> 1;
    const int seg  = ((bid >> 3) << 1) | (bid & 1);   // 0..191 within batch
    const int slot = bb * 192 + seg;                  // unchanged slot layout
    int r_ = seg;
    int i = 0;
    while (r_ >= NS_[i]) { r_ -= NS_[i]; ++i; }
    const int s    = r_;
    const int ns   = NS_[i];
    const int qb   = i << 7;
    const int nkc  = (i + 1) << 2;           // 32-key chunks in causal range
    const int c0   = (nkc * s) / ns;
    const int c1   = (nkc * (s + 1)) / ns;

    const int w    = tid >> 6, lane = tid & 63;
    const int quad = lane >> 4, l15 = lane & 15;
    const size_t bT = (size_t)bb << 12;

    // staging descriptors (K and V both async16, pre-swizzled global src)
    const int kr0 = tid >> 4,          kc0 = tid & 15;
    const int kr1 = (tid + 256) >> 4,  kc1 = (tid + 256) & 15;
    const ushort_t* kp0 = k + (bT + (size_t)c0 * 32 + kr0) * HS_ + ((kc0 ^ (kr0 & 15)) * 8);
    const ushort_t* kp1 = k + (bT + (size_t)c0 * 32 + kr1) * HS_ + ((kc1 ^ (kr1 & 15)) * 8);
    const int vr0 = tid >> 2,          vc0 = tid & 3;
    const int vr1 = (tid + 256) >> 2,  vc1 = (tid + 256) & 3;
    const int vs0 = (vc0 ^ ((vr0 ^ (vr0 >> 2)) & 3));
    const int vs1 = (vc1 ^ ((vr1 ^ (vr1 >> 2)) & 3));
    const ushort_t* vp0 = vT + ((size_t)(bb * HS_) + vr0) * T_ + c0 * 32 + vs0 * 8;
    const ushort_t* vp1 = vT + ((size_t)(bb * HS_) + vr1) * T_ + c0 * 32 + vs1 * 8;

    // Q fragments (A-layout straight from global)
    short8 qf[2][4];
#pragma unroll
    for (int mt = 0; mt < 2; ++mt)
#pragma unroll
        for (int kf = 0; kf < 4; ++kf)
            qf[mt][kf] = *(const short8*)(
                q + (bT + qb + w * 32 + mt * 16 + l15) * HS_ + kf * 32 + quad * 8);

    f32x4 O[2][8];
    f32x4 O_l[2];
#pragma unroll
    for (int mt = 0; mt < 2; ++mt) {
        O_l[mt] = (f32x4)0.f;
#pragma unroll
        for (int nt = 0; nt < 8; ++nt) O[mt][nt] = (f32x4)0.f;
    }
    short8 ones;
#pragma unroll
    for (int e = 0; e < 8; ++e) ones[e] = (short)0x3F80;

    // prologue: stage chunk c0 into buf 0 (K and V via async16)
    {
        async16(kp0, sKb + tid * 8);
        async16(kp1, sKb + (tid + 256) * 8);
        async16(vp0, sVb + tid * 8);
        async16(vp1, sVb + (tid + 256) * 8);
        kp0 += 32 * HS_; kp1 += 32 * HS_; vp0 += 32; vp1 += 32;
    }
    __syncthreads();

    for (int c = c0; c < c1; ++c) {
        const int buf = (c - c0) & 1, nb = buf ^ 1;
        const int kb = c << 5;
        const bool more = (c + 1 < c1);
        if (more) {                          // prefetch chunk c+1 (async)
            async16(kp0, sKb + nb * 4096 + tid * 8);
            async16(kp1, sKb + nb * 4096 + (tid + 256) * 8);
            async16(vp0, sVb + nb * 4096 + tid * 8);
            async16(vp1, sVb + nb * 4096 + (tid + 256) * 8);
            kp0 += 32 * HS_; kp1 += 32 * HS_; vp0 += 32; vp1 += 32;
        }
        const ushort_t* sK = sKb + buf * 4096;
        const ushort_t* sV = sVb + buf * 4096;

        // ---- QK^T (scores in log2 units) ----
        f32x4 S[2][2];
        S[0][0] = (f32x4)0.f; S[0][1] = (f32x4)0.f;
        S[1][0] = (f32x4)0.f; S[1][1] = (f32x4)0.f;
#pragma unroll
        for (int nt = 0; nt < 2; ++nt) {
            int row = nt * 16 + l15;
#pragma unroll
            for (int kf = 0; kf < 4; ++kf) {
                short8 bf = *(const short8*)&sK[row * 128 + (((kf * 4 + quad) ^ l15) * 8)];
                S[0][nt] = __builtin_amdgcn_mfma_f32_16x16x32_bf16(qf[0][kf], bf, S[0][nt], 0, 0, 0);
                S[1][nt] = __builtin_amdgcn_mfma_f32_16x16x32_bf16(qf[1][kf], bf, S[1][nt], 0, 0, 0);
            }
        }
        // ---- causal mask (diagonal chunks only) ----
        if (kb + 31 > qb + w * 32) {
#pragma unroll
            for (int mt = 0; mt < 2; ++mt)
#pragma unroll
                for (int nt = 0; nt < 2; ++nt)
#pragma unroll
                    for (int rr = 0; rr < 4; ++rr)
                        if (kb + nt * 16 + l15 > qb + w * 32 + mt * 16 + quad * 4 + rr)
                            S[mt][nt][rr] = -1e30f;
        }
        // ---- softmax: p = exp2(S) (no max; shift cancels in combine) ----
#pragma unroll
        for (int mt = 0; mt < 2; ++mt)
#pragma unroll
            for (int nt = 0; nt < 2; ++nt)
#pragma unroll
                for (int rr = 0; rr < 4; ++rr)
                    sP[w * 1280 + (mt * 16 + quad * 4 + rr) * 40 + nt * 16 + l15] =
                        f2bf_fast(exp2fast(S[mt][nt][rr]));
        // ---- PV + row-sums via ones-MFMA (vf read once, shared mt) ----
        {
            short8 pf0 = *(short8*)&sP[w * 1280 + (l15) * 40 + quad * 8];
            short8 pf1 = *(short8*)&sP[w * 1280 + (16 + l15) * 40 + quad * 8];
            O_l[0] = __builtin_amdgcn_mfma_f32_16x16x32_bf16(pf0, ones, O_l[0], 0, 0, 0);
            O_l[1] = __builtin_amdgcn_mfma_f32_16x16x32_bf16(pf1, ones, O_l[1], 0, 0, 0);
#pragma unroll
            for (int nt = 0; nt < 8; ++nt) {
                int row = nt * 16 + l15;
                int cch = quad ^ ((row ^ (row >> 2)) & 3);
                short8 vf = *(const short8*)&sV[row * 32 + cch * 8];
                O[0][nt] = __builtin_amdgcn_mfma_f32_16x16x32_bf16(pf0, vf, O[0][nt], 0, 0, 0);
                O[1][nt] = __builtin_amdgcn_mfma_f32_16x16x32_bf16(pf1, vf, O[1][nt], 0, 0, 0);
            }
        }
        __syncthreads();                     // one barrier per chunk
    }

    // ---- epilogue: bf16 partials via LDS coalesce, l from ones-MFMA ----
    ushort_t* sE = smem;                     // 128 x 136 (17408 <= 21504)
#pragma unroll
    for (int mt = 0; mt < 2; ++mt)
#pragma unroll
        for (int nt = 0; nt < 8; ++nt)
#pragma unroll
            for (int rr = 0; rr < 4; ++rr)
                sE[(w * 32 + mt * 16 + quad * 4 + rr) * 136 + nt * 16 + l15] =
                    f2bf(O[mt][nt][rr]);
    if (l15 == 0)
#pragma unroll
        for (int mt = 0; mt < 2; ++mt)
#pragma unroll
            for (int rr = 0; rr < 4; ++rr)
                lseg[slot * 128 + w * 32 + mt * 16 + quad * 4 + rr] = O_l[mt][rr];
    __syncthreads();
#pragma unroll
    for (int j = 0; j < 8; ++j) {
        int d = j * 256 + tid;
        int row = d >> 4, cs = d & 15;
        stnt8(Opart + (size_t)slot * 16384 + row * 128 + cs * 8,
              *(const short8*)&sE[row * 136 + cs * 8]);
    }
}

// ---------------------------------------------------------------------------
// Kernel 4: combine: out = (sum_s O_s) / (sum_s l_s).  grid = 1024.
// ---------------------------------------------------------------------------
__global__ __launch_bounds__(256) void combine_kernel(
    const ushort_t* __restrict__ Opart, const float* __restrict__ lseg,
    float* __restrict__ out)
{
    const int blk  = blockIdx.x;           // 1024
    const int tile = blk >> 3, rg = blk & 7;
    const int i    = tile & 31;
    int sb = (tile >> 5) * 192;
    for (int j = 0; j < i; ++j) sb += NS_[j];
    const int ns  = NS_[i];
    const int row = rg * 16 + (threadIdx.x >> 4);
    const int col = (threadIdx.x & 15) * 8;

    const ushort_t* op = Opart + (size_t)sb * 16384 + row * 128 + col;
    const float*    lp = lseg + sb * 128 + row;

    float den = lp[0];
    short8 cur = *(const short8*)op;
    float acc[8];
#pragma unroll
    for (int e = 0; e < 8; ++e) acc[e] = 0.f;
    for (int s = 1; s < ns; ++s) {
        short8 nxt = *(const short8*)(op + (size_t)s * 16384);
        float  dn  = lp[s * 128];
#pragma unroll
        for (int e = 0; e < 8; ++e) acc[e] += bf2f((ushort_t)cur[e]);
        den += dn;
        cur = nxt;
    }
#pragma unroll
    for (int e = 0; e < 8; ++e) acc[e] += bf2f((ushort_t)cur[e]);

    const float inv = 1.0f / den;
    float* o = out + ((size_t)tile * 128 + row) * 128 + col;
    float4 v0 = make_float4(acc[0] * inv, acc[1] * inv, acc[2] * inv, acc[3] * inv);
    float4 v1 = make_float4(acc[4] * inv, acc[5] * inv, acc[6] * inv, acc[7] * inv);
    *(float4*)o = v0;
    *(float4*)(o + 4) = v1;
}

// ---------------------------------------------------------------------------
extern "C" void kernel_launch(void* const* d_in, const int* in_sizes, int n_in,
                              void* d_out, int out_size, void* d_ws, size_t ws_size,
                              hipStream_t stream)
{
    const float* x  = (const float*)d_in[0];
    const float* Wq = (const float*)d_in[1];
    const float* Wk = (const float*)d_in[2];
    const float* Wv = (const float*)d_in[3];
    float* out = (float*)d_out;

    ushort_t* WT3 = (ushort_t*)d_ws;               // 393,216 shorts
    ushort_t* q   = WT3 + 393216;                  // 2,097,152
    ushort_t* k   = q + 2097152;
    ushort_t* vT  = k + 2097152;                   // [B][HS][T]
    ushort_t* Opart = vT + 2097152;                // 768 slots x 16384 bf16 (25.2 MB)
    float* lseg   = (float*)(Opart + 768 * 16384); // 98,304 floats

    wt_kernel<<<48, 256, 0, stream>>>(Wq, Wk, Wv, WT3);
    qkv_gemm<<<dim3(256, 3), 256, 0, stream>>>(x, WT3, q, k, vT);
    attn_seg<<<768, 256, 0, stream>>>(q, k, vT, Opart, lseg);
    combine_kernel<<<1024, 256, 0, stream>>>(Opart, lseg, out);
}

// Round 11
// 158.638 us; speedup vs baseline: 1.0968x; 1.0095x over previous
//
#include <hip/hip_runtime.h>
#include <hip/hip_bf16.h>
#include <math.h>

typedef __attribute__((ext_vector_type(8))) short short8;
typedef __attribute__((ext_vector_type(4))) float f32x4;
typedef unsigned short ushort_t;

#define B_  4
#define T_  4096
#define C_  1024
#define HS_ 128

// scale folded into q at GEMM epilogue: C^-0.5 * log2(e) -> scores in log2 units
#define QSCALE 0.04508422002778011f

// per-tile segment counts (sum = 192 per batch -> grid 768 = 3 blocks/CU).
__device__ const unsigned char NS_[32] = {
    1,1,1,2,2,2,3,3,3,4,4,4,5,5,5,6,6,7,7,7,8,8,8,9,9,9,10,10,11,11,10,11};

__device__ __forceinline__ ushort_t f2bf(float f) {      // RNE
    unsigned int u = __float_as_uint(f);
    u = (u + 0x7FFFu + ((u >> 16) & 1u)) >> 16;
    return (ushort_t)u;
}
__device__ __forceinline__ ushort_t f2bf_fast(float f) { // positive, ~RNE
    return (ushort_t)((__float_as_uint(f) + 0x8000u) >> 16);
}
__device__ __forceinline__ float bf2f(ushort_t u) {
    return __uint_as_float(((unsigned)u) << 16);
}
__device__ __forceinline__ void async16(const void* g, void* l) {
    __builtin_amdgcn_global_load_lds(
        (const __attribute__((address_space(1))) unsigned int*)g,
        (__attribute__((address_space(3))) unsigned int*)l, 16, 0, 0);
}
__device__ __forceinline__ float exp2fast(float x) {
    return __builtin_amdgcn_exp2f(x);
}
__device__ __forceinline__ void stnt8(ushort_t* p, short8 v) {
    __builtin_nontemporal_store(v, (short8*)p);
}

// ---------------------------------------------------------------------------
// Kernel 1: W [1024][128] fp32 -> WT bf16 [m][h][k] via LDS transpose.
// ---------------------------------------------------------------------------
__global__ __launch_bounds__(256) void wt_kernel(
    const float* __restrict__ Wq, const float* __restrict__ Wk,
    const float* __restrict__ Wv, ushort_t* __restrict__ WT3)
{
    __shared__ ushort_t sWT[128 * 68];
    const int blk = blockIdx.x, tid = threadIdx.x;
    const int m = blk >> 4, slab = blk & 15;
    const float* __restrict__ W = (m == 0) ? Wq : (m == 1) ? Wk : Wv;
    const int kc = slab * 64;
    const int r = tid >> 2, h0 = (tid & 3) * 32;
#pragma unroll
    for (int j = 0; j < 8; ++j) {
        float4 wv = *(const float4*)(W + (size_t)(kc + r) * 128 + h0 + j * 4);
        sWT[(h0 + j * 4 + 0) * 68 + r] = f2bf(wv.x);
        sWT[(h0 + j * 4 + 1) * 68 + r] = f2bf(wv.y);
        sWT[(h0 + j * 4 + 2) * 68 + r] = f2bf(wv.z);
        sWT[(h0 + j * 4 + 3) * 68 + r] = f2bf(wv.w);
    }
    __syncthreads();
#pragma unroll
    for (int j = 0; j < 4; ++j) {
        int d = j * 256 + tid;
        int h = d >> 3, c8 = d & 7;
        short8 o;
#pragma unroll
        for (int e = 0; e < 8; ++e) o[e] = (short)sWT[h * 68 + c8 * 8 + e];
        *(short8*)(WT3 + (size_t)(m * 128 + h) * 1024 + kc + c8 * 8) = o;
    }
}

// ---------------------------------------------------------------------------
// Kernel 2: qkv = x @ W.  64x128 tile, BK=64, double-buffered, (256,3) grid.
// R11: wave repartition 16x128 -> 64x32 (wave w owns cols w*32).  Per-iter
// LDS reads per wave drop 18 -> 12 b128 (-33%): old scheme had every wave
// reading the ENTIRE B-tile (16 b128); now 8 A-reads (4x redundant but A is
// half the bytes) + 4 B-reads.  Same MFMA count, same layout, same sync.
// ---------------------------------------------------------------------------
__global__ __launch_bounds__(256, 3) void qkv_gemm(
    const float* __restrict__ x, const ushort_t* __restrict__ WT3,
    ushort_t* __restrict__ q, ushort_t* __restrict__ k,
    ushort_t* __restrict__ vT)
{
    __shared__ ushort_t smem[24576];      // [2] x (A 4096 | B 8192 shorts)

    const int tid  = threadIdx.x;
    const int t0   = blockIdx.x * 64;
    const int mm   = blockIdx.y;
    const int w    = tid >> 6, lane = tid & 63;
    const int quad = lane >> 4, l15 = lane & 15;

    const ushort_t* __restrict__ WTm = WT3 + (size_t)mm * (128 * 1024);

    const int arow = tid >> 3, ac = tid & 7;
    const float* __restrict__ gx = x + (size_t)(t0 + arow) * C_ + ac * 8;
    const int aswz = ((ac ^ (arow & 7)) * 8);

    const ushort_t* gB[4];
    int bdst[4];
#pragma unroll
    for (int j = 0; j < 4; ++j) {
        int d = j * 256 + tid, row = d >> 3, c = d & 7;
        gB[j] = WTm + (size_t)row * C_ + ((c ^ (row & 7)) * 8);
        bdst[j] = 4096 + d * 8;
    }

    f32x4 acc[4][2];
#pragma unroll
    for (int mt = 0; mt < 4; ++mt)
#pragma unroll
        for (int nt = 0; nt < 2; ++nt) acc[mt][nt] = (f32x4)0.f;

    float4 ar[2][2];
#pragma unroll
    for (int p = 0; p < 2; ++p) {
        ar[p][0] = *(const float4*)(gx + (size_t)(p * 32) * C_);
        ar[p][1] = *(const float4*)(gx + (size_t)(p * 32) * C_ + 4);
    }
#pragma unroll
    for (int j = 0; j < 4; ++j) async16(gB[j], &smem[bdst[j]]);
#pragma unroll
    for (int p = 0; p < 2; ++p) {
        short8 sv;
        sv[0]=f2bf(ar[p][0].x); sv[1]=f2bf(ar[p][0].y);
        sv[2]=f2bf(ar[p][0].z); sv[3]=f2bf(ar[p][0].w);
        sv[4]=f2bf(ar[p][1].x); sv[5]=f2bf(ar[p][1].y);
        sv[6]=f2bf(ar[p][1].z); sv[7]=f2bf(ar[p][1].w);
        *(short8*)&smem[(p * 32 + arow) * 64 + aswz] = sv;
    }
    __syncthreads();

    for (int it = 0; it < 16; ++it) {
        const int buf = it & 1, nb = buf ^ 1;
        const bool more = (it < 15);
        if (more) {
            const int kc = (it + 1) * 64;
#pragma unroll
            for (int p = 0; p < 2; ++p) {
                ar[p][0] = *(const float4*)(gx + (size_t)(p * 32) * C_ + kc);
                ar[p][1] = *(const float4*)(gx + (size_t)(p * 32) * C_ + kc + 4);
            }
#pragma unroll
            for (int j = 0; j < 4; ++j)
                async16(gB[j] + kc, &smem[nb * 12288 + bdst[j]]);
        }
        const ushort_t* sA = &smem[buf * 12288];
        const ushort_t* sB = &smem[buf * 12288 + 4096];
#pragma unroll
        for (int kf = 0; kf < 2; ++kf) {
            const int kc8 = kf * 4 + quad;
            short8 af[4], bfr[2];
#pragma unroll
            for (int mt = 0; mt < 4; ++mt) {
                int r = mt * 16 + l15;
                af[mt] = *(const short8*)&sA[r * 64 + ((kc8 ^ (r & 7)) * 8)];
            }
#pragma unroll
            for (int nt = 0; nt < 2; ++nt) {
                int r = w * 32 + nt * 16 + l15;
                bfr[nt] = *(const short8*)&sB[r * 64 + ((kc8 ^ (r & 7)) * 8)];
            }
#pragma unroll
            for (int mt = 0; mt < 4; ++mt)
#pragma unroll
                for (int nt = 0; nt < 2; ++nt)
                    acc[mt][nt] = __builtin_amdgcn_mfma_f32_16x16x32_bf16(
                        af[mt], bfr[nt], acc[mt][nt], 0, 0, 0);
        }
        if (more) {
#pragma unroll
            for (int p = 0; p < 2; ++p) {
                short8 sv;
                sv[0]=f2bf(ar[p][0].x); sv[1]=f2bf(ar[p][0].y);
                sv[2]=f2bf(ar[p][0].z); sv[3]=f2bf(ar[p][0].w);
                sv[4]=f2bf(ar[p][1].x); sv[5]=f2bf(ar[p][1].y);
                sv[6]=f2bf(ar[p][1].z); sv[7]=f2bf(ar[p][1].w);
                *(short8*)&smem[nb * 12288 + (p * 32 + arow) * 64 + aswz] = sv;
            }
        }
        __syncthreads();
    }

    if (mm < 2) {
        ushort_t* __restrict__ outp = (mm == 0) ? q : k;
        const float s = (mm == 0) ? QSCALE : 1.0f;
        ushort_t* sE = &smem[0];            // 64 x 136
#pragma unroll
        for (int mt = 0; mt < 4; ++mt)
#pragma unroll
            for (int nt = 0; nt < 2; ++nt)
#pragma unroll
                for (int rr = 0; rr < 4; ++rr)
                    sE[(mt * 16 + quad * 4 + rr) * 136 + w * 32 + nt * 16 + l15] =
                        f2bf(acc[mt][nt][rr] * s);
        __syncthreads();
#pragma unroll
        for (int j = 0; j < 4; ++j) {
            int d = j * 256 + tid;
            int row = d >> 4, cs = d & 15;
            *(short8*)(outp + (size_t)(t0 + row) * HS_ + cs * 8) =
                *(const short8*)&sE[row * 136 + cs * 8];
        }
    } else {
        ushort_t* sT = &smem[0];            // 64 x 132
#pragma unroll
        for (int mt = 0; mt < 4; ++mt)
#pragma unroll
            for (int nt = 0; nt < 2; ++nt)
#pragma unroll
                for (int rr = 0; rr < 4; ++rr)
                    sT[(mt * 16 + quad * 4 + rr) * 132 + w * 32 + nt * 16 + l15] =
                        f2bf(acc[mt][nt][rr]);
        __syncthreads();
        const int bb = t0 >> 12;
        const int tl = t0 & (T_ - 1);
#pragma unroll
        for (int j = 0; j < 4; ++j) {
            int d = j * 256 + tid;
            int h = d >> 3, t8 = d & 7;
            short8 o;
#pragma unroll
            for (int e = 0; e < 8; ++e)
                o[e] = (short)sT[(t8 * 8 + e) * 132 + h];
            *(short8*)(vT + ((size_t)(bb * HS_) + h) * T_ + tl + t8 * 8) = o;
        }
    }
}

// ---------------------------------------------------------------------------
// Kernel 3: causal flash attention.  R7 sync; R9 vf-read-once; R10 V via
// async16 with pre-swizzled global source.  (Unchanged this round.)
// ---------------------------------------------------------------------------
__global__ __launch_bounds__(256, 3) void attn_seg(
    const ushort_t* __restrict__ q, const ushort_t* __restrict__ k,
    const ushort_t* __restrict__ vT, ushort_t* __restrict__ Opart,
    float* __restrict__ lseg)
{
    __shared__ ushort_t smem[21504];       // 43 KB
    ushort_t* sKb = smem;                  // [2][4096] : 32 keys x 128 h, swz
    ushort_t* sVb = smem + 8192;           // [2][4096] : 128 h x 32, swz
    ushort_t* sP  = smem + 16384;          // [4][1280] : 32 rows x 40

    const int tid  = threadIdx.x;
    const int bid  = blockIdx.x;
    const int bb   = (bid & 7) >> 1;
    const int seg  = ((bid >> 3) << 1) | (bid & 1);   // 0..191 within batch
    const int slot = bb * 192 + seg;
    int r_ = seg;
    int i = 0;
    while (r_ >= NS_[i]) { r_ -= NS_[i]; ++i; }
    const int s    = r_;
    const int ns   = NS_[i];
    const int qb   = i << 7;
    const int nkc  = (i + 1) << 2;           // 32-key chunks in causal range
    const int c0   = (nkc * s) / ns;
    const int c1   = (nkc * (s + 1)) / ns;

    const int w    = tid >> 6, lane = tid & 63;
    const int quad = lane >> 4, l15 = lane & 15;
    const size_t bT = (size_t)bb << 12;

    // staging descriptors (K and V both async16, pre-swizzled global src)
    const int kr0 = tid >> 4,          kc0 = tid & 15;
    const int kr1 = (tid + 256) >> 4,  kc1 = (tid + 256) & 15;
    const ushort_t* kp0 = k + (bT + (size_t)c0 * 32 + kr0) * HS_ + ((kc0 ^ (kr0 & 15)) * 8);
    const ushort_t* kp1 = k + (bT + (size_t)c0 * 32 + kr1) * HS_ + ((kc1 ^ (kr1 & 15)) * 8);
    const int vr0 = tid >> 2,          vc0 = tid & 3;
    const int vr1 = (tid + 256) >> 2,  vc1 = (tid + 256) & 3;
    const int vs0 = (vc0 ^ ((vr0 ^ (vr0 >> 2)) & 3));
    const int vs1 = (vc1 ^ ((vr1 ^ (vr1 >> 2)) & 3));
    const ushort_t* vp0 = vT + ((size_t)(bb * HS_) + vr0) * T_ + c0 * 32 + vs0 * 8;
    const ushort_t* vp1 = vT + ((size_t)(bb * HS_) + vr1) * T_ + c0 * 32 + vs1 * 8;

    // Q fragments (A-layout straight from global)
    short8 qf[2][4];
#pragma unroll
    for (int mt = 0; mt < 2; ++mt)
#pragma unroll
        for (int kf = 0; kf < 4; ++kf)
            qf[mt][kf] = *(const short8*)(
                q + (bT + qb + w * 32 + mt * 16 + l15) * HS_ + kf * 32 + quad * 8);

    f32x4 O[2][8];
    f32x4 O_l[2];
#pragma unroll
    for (int mt = 0; mt < 2; ++mt) {
        O_l[mt] = (f32x4)0.f;
#pragma unroll
        for (int nt = 0; nt < 8; ++nt) O[mt][nt] = (f32x4)0.f;
    }
    short8 ones;
#pragma unroll
    for (int e = 0; e < 8; ++e) ones[e] = (short)0x3F80;

    // prologue: stage chunk c0 into buf 0 (K and V via async16)
    {
        async16(kp0, sKb + tid * 8);
        async16(kp1, sKb + (tid + 256) * 8);
        async16(vp0, sVb + tid * 8);
        async16(vp1, sVb + (tid + 256) * 8);
        kp0 += 32 * HS_; kp1 += 32 * HS_; vp0 += 32; vp1 += 32;
    }
    __syncthreads();

    for (int c = c0; c < c1; ++c) {
        const int buf = (c - c0) & 1, nb = buf ^ 1;
        const int kb = c << 5;
        const bool more = (c + 1 < c1);
        if (more) {                          // prefetch chunk c+1 (async)
            async16(kp0, sKb + nb * 4096 + tid * 8);
            async16(kp1, sKb + nb * 4096 + (tid + 256) * 8);
            async16(vp0, sVb + nb * 4096 + tid * 8);
            async16(vp1, sVb + nb * 4096 + (tid + 256) * 8);
            kp0 += 32 * HS_; kp1 += 32 * HS_; vp0 += 32; vp1 += 32;
        }
        const ushort_t* sK = sKb + buf * 4096;
        const ushort_t* sV = sVb + buf * 4096;

        // ---- QK^T (scores in log2 units) ----
        f32x4 S[2][2];
        S[0][0] = (f32x4)0.f; S[0][1] = (f32x4)0.f;
        S[1][0] = (f32x4)0.f; S[1][1] = (f32x4)0.f;
#pragma unroll
        for (int nt = 0; nt < 2; ++nt) {
            int row = nt * 16 + l15;
#pragma unroll
            for (int kf = 0; kf < 4; ++kf) {
                short8 bf = *(const short8*)&sK[row * 128 + (((kf * 4 + quad) ^ l15) * 8)];
                S[0][nt] = __builtin_amdgcn_mfma_f32_16x16x32_bf16(qf[0][kf], bf, S[0][nt], 0, 0, 0);
                S[1][nt] = __builtin_amdgcn_mfma_f32_16x16x32_bf16(qf[1][kf], bf, S[1][nt], 0, 0, 0);
            }
        }
        // ---- causal mask (diagonal chunks only) ----
        if (kb + 31 > qb + w * 32) {
#pragma unroll
            for (int mt = 0; mt < 2; ++mt)
#pragma unroll
                for (int nt = 0; nt < 2; ++nt)
#pragma unroll
                    for (int rr = 0; rr < 4; ++rr)
                        if (kb + nt * 16 + l15 > qb + w * 32 + mt * 16 + quad * 4 + rr)
                            S[mt][nt][rr] = -1e30f;
        }
        // ---- softmax: p = exp2(S) (no max; shift cancels in combine) ----
#pragma unroll
        for (int mt = 0; mt < 2; ++mt)
#pragma unroll
            for (int nt = 0; nt < 2; ++nt)
#pragma unroll
                for (int rr = 0; rr < 4; ++rr)
                    sP[w * 1280 + (mt * 16 + quad * 4 + rr) * 40 + nt * 16 + l15] =
                        f2bf_fast(exp2fast(S[mt][nt][rr]));
        // ---- PV + row-sums via ones-MFMA (vf read once, shared mt) ----
        {
            short8 pf0 = *(short8*)&sP[w * 1280 + (l15) * 40 + quad * 8];
            short8 pf1 = *(short8*)&sP[w * 1280 + (16 + l15) * 40 + quad * 8];
            O_l[0] = __builtin_amdgcn_mfma_f32_16x16x32_bf16(pf0, ones, O_l[0], 0, 0, 0);
            O_l[1] = __builtin_amdgcn_mfma_f32_16x16x32_bf16(pf1, ones, O_l[1], 0, 0, 0);
#pragma unroll
            for (int nt = 0; nt < 8; ++nt) {
                int row = nt * 16 + l15;
                int cch = quad ^ ((row ^ (row >> 2)) & 3);
                short8 vf = *(const short8*)&sV[row * 32 + cch * 8];
                O[0][nt] = __builtin_amdgcn_mfma_f32_16x16x32_bf16(pf0, vf, O[0][nt], 0, 0, 0);
                O[1][nt] = __builtin_amdgcn_mfma_f32_16x16x32_bf16(pf1, vf, O[1][nt], 0, 0, 0);
            }
        }
        __syncthreads();                     // one barrier per chunk
    }

    // ---- epilogue: bf16 partials via LDS coalesce, l from ones-MFMA ----
    ushort_t* sE = smem;                     // 128 x 136 (17408 <= 21504)
#pragma unroll
    for (int mt = 0; mt < 2; ++mt)
#pragma unroll
        for (int nt = 0; nt < 8; ++nt)
#pragma unroll
            for (int rr = 0; rr < 4; ++rr)
                sE[(w * 32 + mt * 16 + quad * 4 + rr) * 136 + nt * 16 + l15] =
                    f2bf(O[mt][nt][rr]);
    if (l15 == 0)
#pragma unroll
        for (int mt = 0; mt < 2; ++mt)
#pragma unroll
            for (int rr = 0; rr < 4; ++rr)
                lseg[slot * 128 + w * 32 + mt * 16 + quad * 4 + rr] = O_l[mt][rr];
    __syncthreads();
#pragma unroll
    for (int j = 0; j < 8; ++j) {
        int d = j * 256 + tid;
        int row = d >> 4, cs = d & 15;
        stnt8(Opart + (size_t)slot * 16384 + row * 128 + cs * 8,
              *(const short8*)&sE[row * 136 + cs * 8]);
    }
}

// ---------------------------------------------------------------------------
// Kernel 4: combine: out = (sum_s O_s) / (sum_s l_s).  grid = 1024.
// ---------------------------------------------------------------------------
__global__ __launch_bounds__(256) void combine_kernel(
    const ushort_t* __restrict__ Opart, const float* __restrict__ lseg,
    float* __restrict__ out)
{
    const int blk  = blockIdx.x;           // 1024
    const int tile = blk >> 3, rg = blk & 7;
    const int i    = tile & 31;
    int sb = (tile >> 5) * 192;
    for (int j = 0; j < i; ++j) sb += NS_[j];
    const int ns  = NS_[i];
    const int row = rg * 16 + (threadIdx.x >> 4);
    const int col = (threadIdx.x & 15) * 8;

    const ushort_t* op = Opart + (size_t)sb * 16384 + row * 128 + col;
    const float*    lp = lseg + sb * 128 + row;

    float den = lp[0];
    short8 cur = *(const short8*)op;
    float acc[8];
#pragma unroll
    for (int e = 0; e < 8; ++e) acc[e] = 0.f;
    for (int s = 1; s < ns; ++s) {
        short8 nxt = *(const short8*)(op + (size_t)s * 16384);
        float  dn  = lp[s * 128];
#pragma unroll
        for (int e = 0; e < 8; ++e) acc[e] += bf2f((ushort_t)cur[e]);
        den += dn;
        cur = nxt;
    }
#pragma unroll
    for (int e = 0; e < 8; ++e) acc[e] += bf2f((ushort_t)cur[e]);

    const float inv = 1.0f / den;
    float* o = out + ((size_t)tile * 128 + row) * 128 + col;
    float4 v0 = make_float4(acc[0] * inv, acc[1] * inv, acc[2] * inv, acc[3] * inv);
    float4 v1 = make_float4(acc[4] * inv, acc[5] * inv, acc[6] * inv, acc[7] * inv);
    *(float4*)o = v0;
    *(float4*)(o + 4) = v1;
}

// ---------------------------------------------------------------------------
extern "C" void kernel_launch(void* const* d_in, const int* in_sizes, int n_in,
                              void* d_out, int out_size, void* d_ws, size_t ws_size,
                              hipStream_t stream)
{
    const float* x  = (const float*)d_in[0];
    const float* Wq = (const float*)d_in[1];
    const float* Wk = (const float*)d_in[2];
    const float* Wv = (const float*)d_in[3];
    float* out = (float*)d_out;

    ushort_t* WT3 = (ushort_t*)d_ws;               // 393,216 shorts
    ushort_t* q   = WT3 + 393216;                  // 2,097,152
    ushort_t* k   = q + 2097152;
    ushort_t* vT  = k + 2097152;                   // [B][HS][T]
    ushort_t* Opart = vT + 2097152;                // 768 slots x 16384 bf16 (25.2 MB)
    float* lseg   = (float*)(Opart + 768 * 16384); // 98,304 floats

    wt_kernel<<<48, 256, 0, stream>>>(Wq, Wk, Wv, WT3);
    qkv_gemm<<<dim3(256, 3), 256, 0, stream>>>(x, WT3, q, k, vT);
    attn_seg<<<768, 256, 0, stream>>>(q, k, vT, Opart, lseg);
    combine_kernel<<<1024, 256, 0, stream>>>(Opart, lseg, out);
}

// Round 12
// 156.132 us; speedup vs baseline: 1.1144x; 1.0160x over previous
//
#include <hip/hip_runtime.h>
#include <hip/hip_bf16.h>
#include <math.h>

typedef __attribute__((ext_vector_type(8))) short short8;
typedef __attribute__((ext_vector_type(4))) short short4v;
typedef __attribute__((ext_vector_type(4))) float f32x4;
typedef unsigned short ushort_t;

#define B_  4
#define T_  4096
#define C_  1024
#define HS_ 128

// scale folded into q at GEMM epilogue: C^-0.5 * log2(e) -> scores in log2 units
#define QSCALE 0.04508422002778011f

// per-tile segment counts (sum = 192 per batch -> grid 768 = 3 blocks/CU).
__device__ const unsigned char NS_[32] = {
    1,1,1,2,2,2,3,3,3,4,4,4,5,5,5,6,6,7,7,7,8,8,8,9,9,9,10,10,11,11,10,11};

__device__ __forceinline__ ushort_t f2bf(float f) {      // RNE
    unsigned int u = __float_as_uint(f);
    u = (u + 0x7FFFu + ((u >> 16) & 1u)) >> 16;
    return (ushort_t)u;
}
__device__ __forceinline__ ushort_t f2bf_fast(float f) { // positive, ~RNE
    return (ushort_t)((__float_as_uint(f) + 0x8000u) >> 16);
}
__device__ __forceinline__ float bf2f(ushort_t u) {
    return __uint_as_float(((unsigned)u) << 16);
}
__device__ __forceinline__ void async16(const void* g, void* l) {
    __builtin_amdgcn_global_load_lds(
        (const __attribute__((address_space(1))) unsigned int*)g,
        (__attribute__((address_space(3))) unsigned int*)l, 16, 0, 0);
}
__device__ __forceinline__ float exp2fast(float x) {
    return __builtin_amdgcn_exp2f(x);
}
__device__ __forceinline__ void stnt8(ushort_t* p, short8 v) {
    __builtin_nontemporal_store(v, (short8*)p);
}

// ---------------------------------------------------------------------------
// Kernel 1: W [1024][128] fp32 -> WT bf16 [m][h][k] via LDS transpose.
// ---------------------------------------------------------------------------
__global__ __launch_bounds__(256) void wt_kernel(
    const float* __restrict__ Wq, const float* __restrict__ Wk,
    const float* __restrict__ Wv, ushort_t* __restrict__ WT3)
{
    __shared__ ushort_t sWT[128 * 68];
    const int blk = blockIdx.x, tid = threadIdx.x;
    const int m = blk >> 4, slab = blk & 15;
    const float* __restrict__ W = (m == 0) ? Wq : (m == 1) ? Wk : Wv;
    const int kc = slab * 64;
    const int r = tid >> 2, h0 = (tid & 3) * 32;
#pragma unroll
    for (int j = 0; j < 8; ++j) {
        float4 wv = *(const float4*)(W + (size_t)(kc + r) * 128 + h0 + j * 4);
        sWT[(h0 + j * 4 + 0) * 68 + r] = f2bf(wv.x);
        sWT[(h0 + j * 4 + 1) * 68 + r] = f2bf(wv.y);
        sWT[(h0 + j * 4 + 2) * 68 + r] = f2bf(wv.z);
        sWT[(h0 + j * 4 + 3) * 68 + r] = f2bf(wv.w);
    }
    __syncthreads();
#pragma unroll
    for (int j = 0; j < 4; ++j) {
        int d = j * 256 + tid;
        int h = d >> 3, c8 = d & 7;
        short8 o;
#pragma unroll
        for (int e = 0; e < 8; ++e) o[e] = (short)sWT[h * 68 + c8 * 8 + e];
        *(short8*)(WT3 + (size_t)(m * 128 + h) * 1024 + kc + c8 * 8) = o;
    }
}

// ---------------------------------------------------------------------------
// Kernel 2: qkv = x @ W.  64x128 tile, BK=64, double-buffered, (256,3) grid.
// R11 wave repartition (64x32 per wave): 12 b128 LDS reads/iter/wave.
// ---------------------------------------------------------------------------
__global__ __launch_bounds__(256, 3) void qkv_gemm(
    const float* __restrict__ x, const ushort_t* __restrict__ WT3,
    ushort_t* __restrict__ q, ushort_t* __restrict__ k,
    ushort_t* __restrict__ vT)
{
    __shared__ ushort_t smem[24576];      // [2] x (A 4096 | B 8192 shorts)

    const int tid  = threadIdx.x;
    const int t0   = blockIdx.x * 64;
    const int mm   = blockIdx.y;
    const int w    = tid >> 6, lane = tid & 63;
    const int quad = lane >> 4, l15 = lane & 15;

    const ushort_t* __restrict__ WTm = WT3 + (size_t)mm * (128 * 1024);

    const int arow = tid >> 3, ac = tid & 7;
    const float* __restrict__ gx = x + (size_t)(t0 + arow) * C_ + ac * 8;
    const int aswz = ((ac ^ (arow & 7)) * 8);

    const ushort_t* gB[4];
    int bdst[4];
#pragma unroll
    for (int j = 0; j < 4; ++j) {
        int d = j * 256 + tid, row = d >> 3, c = d & 7;
        gB[j] = WTm + (size_t)row * C_ + ((c ^ (row & 7)) * 8);
        bdst[j] = 4096 + d * 8;
    }

    f32x4 acc[4][2];
#pragma unroll
    for (int mt = 0; mt < 4; ++mt)
#pragma unroll
        for (int nt = 0; nt < 2; ++nt) acc[mt][nt] = (f32x4)0.f;

    float4 ar[2][2];
#pragma unroll
    for (int p = 0; p < 2; ++p) {
        ar[p][0] = *(const float4*)(gx + (size_t)(p * 32) * C_);
        ar[p][1] = *(const float4*)(gx + (size_t)(p * 32) * C_ + 4);
    }
#pragma unroll
    for (int j = 0; j < 4; ++j) async16(gB[j], &smem[bdst[j]]);
#pragma unroll
    for (int p = 0; p < 2; ++p) {
        short8 sv;
        sv[0]=f2bf(ar[p][0].x); sv[1]=f2bf(ar[p][0].y);
        sv[2]=f2bf(ar[p][0].z); sv[3]=f2bf(ar[p][0].w);
        sv[4]=f2bf(ar[p][1].x); sv[5]=f2bf(ar[p][1].y);
        sv[6]=f2bf(ar[p][1].z); sv[7]=f2bf(ar[p][1].w);
        *(short8*)&smem[(p * 32 + arow) * 64 + aswz] = sv;
    }
    __syncthreads();

    for (int it = 0; it < 16; ++it) {
        const int buf = it & 1, nb = buf ^ 1;
        const bool more = (it < 15);
        if (more) {
            const int kc = (it + 1) * 64;
#pragma unroll
            for (int p = 0; p < 2; ++p) {
                ar[p][0] = *(const float4*)(gx + (size_t)(p * 32) * C_ + kc);
                ar[p][1] = *(const float4*)(gx + (size_t)(p * 32) * C_ + kc + 4);
            }
#pragma unroll
            for (int j = 0; j < 4; ++j)
                async16(gB[j] + kc, &smem[nb * 12288 + bdst[j]]);
        }
        const ushort_t* sA = &smem[buf * 12288];
        const ushort_t* sB = &smem[buf * 12288 + 4096];
#pragma unroll
        for (int kf = 0; kf < 2; ++kf) {
            const int kc8 = kf * 4 + quad;
            short8 af[4], bfr[2];
#pragma unroll
            for (int mt = 0; mt < 4; ++mt) {
                int r = mt * 16 + l15;
                af[mt] = *(const short8*)&sA[r * 64 + ((kc8 ^ (r & 7)) * 8)];
            }
#pragma unroll
            for (int nt = 0; nt < 2; ++nt) {
                int r = w * 32 + nt * 16 + l15;
                bfr[nt] = *(const short8*)&sB[r * 64 + ((kc8 ^ (r & 7)) * 8)];
            }
#pragma unroll
            for (int mt = 0; mt < 4; ++mt)
#pragma unroll
                for (int nt = 0; nt < 2; ++nt)
                    acc[mt][nt] = __builtin_amdgcn_mfma_f32_16x16x32_bf16(
                        af[mt], bfr[nt], acc[mt][nt], 0, 0, 0);
        }
        if (more) {
#pragma unroll
            for (int p = 0; p < 2; ++p) {
                short8 sv;
                sv[0]=f2bf(ar[p][0].x); sv[1]=f2bf(ar[p][0].y);
                sv[2]=f2bf(ar[p][0].z); sv[3]=f2bf(ar[p][0].w);
                sv[4]=f2bf(ar[p][1].x); sv[5]=f2bf(ar[p][1].y);
                sv[6]=f2bf(ar[p][1].z); sv[7]=f2bf(ar[p][1].w);
                *(short8*)&smem[nb * 12288 + (p * 32 + arow) * 64 + aswz] = sv;
            }
        }
        __syncthreads();
    }

    if (mm < 2) {
        ushort_t* __restrict__ outp = (mm == 0) ? q : k;
        const float s = (mm == 0) ? QSCALE : 1.0f;
        ushort_t* sE = &smem[0];            // 64 x 136
#pragma unroll
        for (int mt = 0; mt < 4; ++mt)
#pragma unroll
            for (int nt = 0; nt < 2; ++nt)
#pragma unroll
                for (int rr = 0; rr < 4; ++rr)
                    sE[(mt * 16 + quad * 4 + rr) * 136 + w * 32 + nt * 16 + l15] =
                        f2bf(acc[mt][nt][rr] * s);
        __syncthreads();
#pragma unroll
        for (int j = 0; j < 4; ++j) {
            int d = j * 256 + tid;
            int row = d >> 4, cs = d & 15;
            *(short8*)(outp + (size_t)(t0 + row) * HS_ + cs * 8) =
                *(const short8*)&sE[row * 136 + cs * 8];
        }
    } else {
        ushort_t* sT = &smem[0];            // 64 x 132
#pragma unroll
        for (int mt = 0; mt < 4; ++mt)
#pragma unroll
            for (int nt = 0; nt < 2; ++nt)
#pragma unroll
                for (int rr = 0; rr < 4; ++rr)
                    sT[(mt * 16 + quad * 4 + rr) * 132 + w * 32 + nt * 16 + l15] =
                        f2bf(acc[mt][nt][rr]);
        __syncthreads();
        const int bb = t0 >> 12;
        const int tl = t0 & (T_ - 1);
#pragma unroll
        for (int j = 0; j < 4; ++j) {
            int d = j * 256 + tid;
            int h = d >> 3, t8 = d & 7;
            short8 o;
#pragma unroll
            for (int e = 0; e < 8; ++e)
                o[e] = (short)sT[(t8 * 8 + e) * 132 + h];
            *(short8*)(vT + ((size_t)(bb * HS_) + h) * T_ + tl + t8 * 8) = o;
        }
    }
}

// ---------------------------------------------------------------------------
// Kernel 3: causal flash attention.  R7 sync; R9 vf-read-once; R10 V async16.
// R12: SWAPPED QK^T — compute mfma(K, Q) instead of mfma(Q, K).  K's LDS
// read already has the A-fragment shape and Q's register fragment the B
// shape, so the swap is free; the C-layout transposes to lane = P[q=l15]
// [kv=quad*4+rr] -> 4 CONSECUTIVE kv per lane -> P spill becomes 4
// ds_write_b64 (short4) instead of 16 scalar ds_write_b16 (2-way bank =
// free; lanes l15/l15+8 share a pair).  Mask indices swapped to match.
// pf read-back, PV, ones-MFMA, epilogue unchanged.
// ---------------------------------------------------------------------------
__global__ __launch_bounds__(256, 3) void attn_seg(
    const ushort_t* __restrict__ q, const ushort_t* __restrict__ k,
    const ushort_t* __restrict__ vT, ushort_t* __restrict__ Opart,
    float* __restrict__ lseg)
{
    __shared__ ushort_t smem[21504];       // 43 KB
    ushort_t* sKb = smem;                  // [2][4096] : 32 keys x 128 h, swz
    ushort_t* sVb = smem + 8192;           // [2][4096] : 128 h x 32, swz
    ushort_t* sP  = smem + 16384;          // [4][1280] : 32 q-rows x 40 kv

    const int tid  = threadIdx.x;
    const int bid  = blockIdx.x;
    const int bb   = (bid & 7) >> 1;
    const int seg  = ((bid >> 3) << 1) | (bid & 1);   // 0..191 within batch
    const int slot = bb * 192 + seg;
    int r_ = seg;
    int i = 0;
    while (r_ >= NS_[i]) { r_ -= NS_[i]; ++i; }
    const int s    = r_;
    const int ns   = NS_[i];
    const int qb   = i << 7;
    const int nkc  = (i + 1) << 2;           // 32-key chunks in causal range
    const int c0   = (nkc * s) / ns;
    const int c1   = (nkc * (s + 1)) / ns;

    const int w    = tid >> 6, lane = tid & 63;
    const int quad = lane >> 4, l15 = lane & 15;
    const size_t bT = (size_t)bb << 12;

    // staging descriptors (K and V both async16, pre-swizzled global src)
    const int kr0 = tid >> 4,          kc0 = tid & 15;
    const int kr1 = (tid + 256) >> 4,  kc1 = (tid + 256) & 15;
    const ushort_t* kp0 = k + (bT + (size_t)c0 * 32 + kr0) * HS_ + ((kc0 ^ (kr0 & 15)) * 8);
    const ushort_t* kp1 = k + (bT + (size_t)c0 * 32 + kr1) * HS_ + ((kc1 ^ (kr1 & 15)) * 8);
    const int vr0 = tid >> 2,          vc0 = tid & 3;
    const int vr1 = (tid + 256) >> 2,  vc1 = (tid + 256) & 3;
    const int vs0 = (vc0 ^ ((vr0 ^ (vr0 >> 2)) & 3));
    const int vs1 = (vc1 ^ ((vr1 ^ (vr1 >> 2)) & 3));
    const ushort_t* vp0 = vT + ((size_t)(bb * HS_) + vr0) * T_ + c0 * 32 + vs0 * 8;
    const ushort_t* vp1 = vT + ((size_t)(bb * HS_) + vr1) * T_ + c0 * 32 + vs1 * 8;

    // Q fragments (A-layout straight from global; used as B-operand when swapped)
    short8 qf[2][4];
#pragma unroll
    for (int mt = 0; mt < 2; ++mt)
#pragma unroll
        for (int kf = 0; kf < 4; ++kf)
            qf[mt][kf] = *(const short8*)(
                q + (bT + qb + w * 32 + mt * 16 + l15) * HS_ + kf * 32 + quad * 8);

    f32x4 O[2][8];
    f32x4 O_l[2];
#pragma unroll
    for (int mt = 0; mt < 2; ++mt) {
        O_l[mt] = (f32x4)0.f;
#pragma unroll
        for (int nt = 0; nt < 8; ++nt) O[mt][nt] = (f32x4)0.f;
    }
    short8 ones;
#pragma unroll
    for (int e = 0; e < 8; ++e) ones[e] = (short)0x3F80;

    // prologue: stage chunk c0 into buf 0 (K and V via async16)
    {
        async16(kp0, sKb + tid * 8);
        async16(kp1, sKb + (tid + 256) * 8);
        async16(vp0, sVb + tid * 8);
        async16(vp1, sVb + (tid + 256) * 8);
        kp0 += 32 * HS_; kp1 += 32 * HS_; vp0 += 32; vp1 += 32;
    }
    __syncthreads();

    for (int c = c0; c < c1; ++c) {
        const int buf = (c - c0) & 1, nb = buf ^ 1;
        const int kb = c << 5;
        const bool more = (c + 1 < c1);
        if (more) {                          // prefetch chunk c+1 (async)
            async16(kp0, sKb + nb * 4096 + tid * 8);
            async16(kp1, sKb + nb * 4096 + (tid + 256) * 8);
            async16(vp0, sVb + nb * 4096 + tid * 8);
            async16(vp1, sVb + nb * 4096 + (tid + 256) * 8);
            kp0 += 32 * HS_; kp1 += 32 * HS_; vp0 += 32; vp1 += 32;
        }
        const ushort_t* sK = sKb + buf * 4096;
        const ushort_t* sV = sVb + buf * 4096;

        // ---- QK^T SWAPPED: S[mt][nt] = mfma(K, Q) -> lane holds
        //      P[q = mt*16+l15][kv = nt*16+quad*4+rr]  (scores, log2 units)
        f32x4 S[2][2];
        S[0][0] = (f32x4)0.f; S[0][1] = (f32x4)0.f;
        S[1][0] = (f32x4)0.f; S[1][1] = (f32x4)0.f;
#pragma unroll
        for (int nt = 0; nt < 2; ++nt) {
            int row = nt * 16 + l15;
#pragma unroll
            for (int kf = 0; kf < 4; ++kf) {
                short8 kfr = *(const short8*)&sK[row * 128 + (((kf * 4 + quad) ^ l15) * 8)];
                S[0][nt] = __builtin_amdgcn_mfma_f32_16x16x32_bf16(kfr, qf[0][kf], S[0][nt], 0, 0, 0);
                S[1][nt] = __builtin_amdgcn_mfma_f32_16x16x32_bf16(kfr, qf[1][kf], S[1][nt], 0, 0, 0);
            }
        }
        // ---- causal mask (diagonal chunks only; swapped indices) ----
        if (kb + 31 > qb + w * 32) {
#pragma unroll
            for (int mt = 0; mt < 2; ++mt)
#pragma unroll
                for (int nt = 0; nt < 2; ++nt)
#pragma unroll
                    for (int rr = 0; rr < 4; ++rr)
                        if (kb + nt * 16 + quad * 4 + rr > qb + w * 32 + mt * 16 + l15)
                            S[mt][nt][rr] = -1e30f;
        }
        // ---- softmax: p = exp2(S); packed b64 spill (4 writes, was 16) ----
#pragma unroll
        for (int mt = 0; mt < 2; ++mt)
#pragma unroll
            for (int nt = 0; nt < 2; ++nt) {
                short4v pv;
#pragma unroll
                for (int rr = 0; rr < 4; ++rr)
                    pv[rr] = (short)f2bf_fast(exp2fast(S[mt][nt][rr]));
                *(short4v*)&sP[w * 1280 + (mt * 16 + l15) * 40 + nt * 16 + quad * 4] = pv;
            }
        // ---- PV + row-sums via ones-MFMA (vf read once, shared mt) ----
        {
            short8 pf0 = *(short8*)&sP[w * 1280 + (l15) * 40 + quad * 8];
            short8 pf1 = *(short8*)&sP[w * 1280 + (16 + l15) * 40 + quad * 8];
            O_l[0] = __builtin_amdgcn_mfma_f32_16x16x32_bf16(pf0, ones, O_l[0], 0, 0, 0);
            O_l[1] = __builtin_amdgcn_mfma_f32_16x16x32_bf16(pf1, ones, O_l[1], 0, 0, 0);
#pragma unroll
            for (int nt = 0; nt < 8; ++nt) {
                int row = nt * 16 + l15;
                int cch = quad ^ ((row ^ (row >> 2)) & 3);
                short8 vf = *(const short8*)&sV[row * 32 + cch * 8];
                O[0][nt] = __builtin_amdgcn_mfma_f32_16x16x32_bf16(pf0, vf, O[0][nt], 0, 0, 0);
                O[1][nt] = __builtin_amdgcn_mfma_f32_16x16x32_bf16(pf1, vf, O[1][nt], 0, 0, 0);
            }
        }
        __syncthreads();                     // one barrier per chunk
    }

    // ---- epilogue: bf16 partials via LDS coalesce, l from ones-MFMA ----
    ushort_t* sE = smem;                     // 128 x 136 (17408 <= 21504)
#pragma unroll
    for (int mt = 0; mt < 2; ++mt)
#pragma unroll
        for (int nt = 0; nt < 8; ++nt)
#pragma unroll
            for (int rr = 0; rr < 4; ++rr)
                sE[(w * 32 + mt * 16 + quad * 4 + rr) * 136 + nt * 16 + l15] =
                    f2bf(O[mt][nt][rr]);
    if (l15 == 0)
#pragma unroll
        for (int mt = 0; mt < 2; ++mt)
#pragma unroll
            for (int rr = 0; rr < 4; ++rr)
                lseg[slot * 128 + w * 32 + mt * 16 + quad * 4 + rr] = O_l[mt][rr];
    __syncthreads();
#pragma unroll
    for (int j = 0; j < 8; ++j) {
        int d = j * 256 + tid;
        int row = d >> 4, cs = d & 15;
        stnt8(Opart + (size_t)slot * 16384 + row * 128 + cs * 8,
              *(const short8*)&sE[row * 136 + cs * 8]);
    }
}

// ---------------------------------------------------------------------------
// Kernel 4: combine: out = (sum_s O_s) / (sum_s l_s).  grid = 1024.
// ---------------------------------------------------------------------------
__global__ __launch_bounds__(256) void combine_kernel(
    const ushort_t* __restrict__ Opart, const float* __restrict__ lseg,
    float* __restrict__ out)
{
    const int blk  = blockIdx.x;           // 1024
    const int tile = blk >> 3, rg = blk & 7;
    const int i    = tile & 31;
    int sb = (tile >> 5) * 192;
    for (int j = 0; j < i; ++j) sb += NS_[j];
    const int ns  = NS_[i];
    const int row = rg * 16 + (threadIdx.x >> 4);
    const int col = (threadIdx.x & 15) * 8;

    const ushort_t* op = Opart + (size_t)sb * 16384 + row * 128 + col;
    const float*    lp = lseg + sb * 128 + row;

    float den = lp[0];
    short8 cur = *(const short8*)op;
    float acc[8];
#pragma unroll
    for (int e = 0; e < 8; ++e) acc[e] = 0.f;
    for (int s = 1; s < ns; ++s) {
        short8 nxt = *(const short8*)(op + (size_t)s * 16384);
        float  dn  = lp[s * 128];
#pragma unroll
        for (int e = 0; e < 8; ++e) acc[e] += bf2f((ushort_t)cur[e]);
        den += dn;
        cur = nxt;
    }
#pragma unroll
    for (int e = 0; e < 8; ++e) acc[e] += bf2f((ushort_t)cur[e]);

    const float inv = 1.0f / den;
    float* o = out + ((size_t)tile * 128 + row) * 128 + col;
    float4 v0 = make_float4(acc[0] * inv, acc[1] * inv, acc[2] * inv, acc[3] * inv);
    float4 v1 = make_float4(acc[4] * inv, acc[5] * inv, acc[6] * inv, acc[7] * inv);
    *(float4*)o = v0;
    *(float4*)(o + 4) = v1;
}

// ---------------------------------------------------------------------------
extern "C" void kernel_launch(void* const* d_in, const int* in_sizes, int n_in,
                              void* d_out, int out_size, void* d_ws, size_t ws_size,
                              hipStream_t stream)
{
    const float* x  = (const float*)d_in[0];
    const float* Wq = (const float*)d_in[1];
    const float* Wk = (const float*)d_in[2];
    const float* Wv = (const float*)d_in[3];
    float* out = (float*)d_out;

    ushort_t* WT3 = (ushort_t*)d_ws;               // 393,216 shorts
    ushort_t* q   = WT3 + 393216;                  // 2,097,152
    ushort_t* k   = q + 2097152;
    ushort_t* vT  = k + 2097152;                   // [B][HS][T]
    ushort_t* Opart = vT + 2097152;                // 768 slots x 16384 bf16 (25.2 MB)
    float* lseg   = (float*)(Opart + 768 * 16384); // 98,304 floats

    wt_kernel<<<48, 256, 0, stream>>>(Wq, Wk, Wv, WT3);
    qkv_gemm<<<dim3(256, 3), 256, 0, stream>>>(x, WT3, q, k, vT);
    attn_seg<<<768, 256, 0, stream>>>(q, k, vT, Opart, lseg);
    combine_kernel<<<1024, 256, 0, stream>>>(Opart, lseg, out);
}